// Round 8
// baseline (2452.955 us; speedup 1.0000x reference)
//
#include <hip/hip_runtime.h>

#define NB 112
#define SEQ 128
#define DM 768
#define NH 12
#define HD 64
#define FF 3072
#define NLAYER 3
#define MTOK (NB*SEQ)            // 14336
#define QKVN (3*DM)              // 2304
#define HEADTOT (NB*NH)          // 1344
#define QSZ ((size_t)HEADTOT*SEQ*HD)   // 11010048 elems per q/k/v

typedef unsigned short u16;
typedef __attribute__((ext_vector_type(8))) short short8;
typedef __attribute__((ext_vector_type(4))) float f32x4;
typedef __attribute__((ext_vector_type(4))) unsigned short us4;

__device__ __forceinline__ u16 f2bf(float f){
  unsigned u = __builtin_bit_cast(unsigned, f);
  u += 0x7FFFu + ((u >> 16) & 1u);
  return (u16)(u >> 16);
}
__device__ __forceinline__ float bf2f(u16 b){
  unsigned u = ((unsigned)b) << 16;
  return __builtin_bit_cast(float, u);
}
__device__ __forceinline__ unsigned cvt_pk_bf16(float lo, float hi){
  unsigned r;
  asm("v_cvt_pk_bf16_f32 %0, %1, %2" : "=v"(r) : "v"(lo), "v"(hi));
  return r;
}
// tanh-GELU in sigmoid form: 0.5x(1+tanh(z)) == x / (1 + e^{-2z})
__device__ __forceinline__ float gelu_t(float x){
  const float t = -1.5957691216057308f * x * __builtin_fmaf(0.044715f, x*x, 1.0f);
  return __fdividef(x, 1.0f + __expf(t));
}

__device__ __forceinline__ void gl_lds16(const void* g, void* l){
  __builtin_amdgcn_global_load_lds((const __attribute__((address_space(1))) unsigned*)g,
                                   (__attribute__((address_space(3))) unsigned*)l, 16, 0, 0);
}

// ================= persistent 256x256 8-phase GEMM ===========================
// C[m,n] = sum_k A[m,k]*W[n,k]. 512 thr = 8 waves (2M x 4N).
// XCD-consistent m-panel ownership: XCD x (= blockIdx & 7, HW round-robin)
// owns m-panels [7x, 7x+7) in EVERY GEMM -> activations are written and
// re-read on the same XCD (local-L2 producer->consumer), avoiding cross-XCD
// dirty-line reads (round-6/7 regression mechanism). n-fastest within panel.
// EPI: 1 = gelu(acc+bias)->bf16
//      2 = y=acc+bias+(rsc*res+rsh) -> bf16 + BN partials   (intermediate)
//      3 = qkv head-scatter bf16
//      4 = same as 2 but f32 out (final layer)
template<int EPI>
__global__ __launch_bounds__(512, 2)
void gemm_bt(const u16* __restrict__ A, const u16* __restrict__ W,
             const float* __restrict__ bias, u16* __restrict__ obf,
             float* __restrict__ of32, const u16* __restrict__ res,
             const float* __restrict__ rsc, const float* __restrict__ rsh,
             float* __restrict__ p1, float* __restrict__ p2,
             int M, int N, int K, int Nt, int TPB)
{
  __shared__ __align__(16) char smem[131072];
  const int tid = threadIdx.x;
  const int w = tid >> 6, lane = tid & 63;
  const int wm = w >> 2, wn = w & 3;
  const int fr = lane & 15, fg = lane >> 4;
  const int fko = fg * 8;
  const int xcd = blockIdx.x & 7, pos = blockIdx.x >> 3;
  const int nt = K >> 6;
  const int tot = TPB * nt;
  const int l3 = lane >> 3;
  const int k16s = ((lane & 7) ^ l3) * 8;
  int rowAK[2][2], rowBK[2][2];
  #pragma unroll
  for (int mh = 0; mh < 2; mh++)
    #pragma unroll
    for (int j = 0; j < 2; j++)
      rowAK[mh][j] = (mh*64 + j*128 + w*8 + l3) * K;
  #pragma unroll
  for (int h = 0; h < 2; h++)
    #pragma unroll
    for (int j = 0; j < 2; j++)
      rowBK[h][j] = (h*128 + (w + j*8)*8 + l3) * K;

  auto stA2 = [&](int bb, int mh, int soff) {
    const u16* g0 = A + (size_t)soff + rowAK[mh][0] + k16s;
    const u16* g1 = A + (size_t)soff + rowAK[mh][1] + k16s;
    char* d = smem + bb*65536 + (mh*64 + w*8)*128;
    gl_lds16(g0, d);
    gl_lds16(g1, d + 16384);
  };
  auto stB2 = [&](int bb, int h, int soff) {
    const u16* g0 = W + (size_t)soff + rowBK[h][0] + k16s;
    const u16* g1 = W + (size_t)soff + rowBK[h][1] + k16s;
    char* d = smem + bb*65536 + 32768 + (h*128 + w*8)*128;
    gl_lds16(g0, d);
    gl_lds16(g1, d + 8192);
  };
  const int axor = (fr & 7) << 4;
  auto rdA2 = [&](int bb, int mh, int kh, int mf) -> short8 {
    const int row = wm*128 + mh*64 + mf*16 + fr;
    return *(const short8*)(smem + bb*65536 + row*128 + (((kh*32 + fko)*2) ^ axor));
  };
  auto rdB2 = [&](int bb, int kh, int nf) -> short8 {
    const int row = wn*64 + nf*16 + fr;
    return *(const short8*)(smem + bb*65536 + 32768 + row*128 + (((kh*32 + fko)*2) ^ axor));
  };
  // XCD x owns m-panels [7x, 7x+7); block iterates n-fastest within panel
  auto coord = [&](int r, int& bm, int& bn) {
    const int t = pos * TPB + r;          // local tile index within this XCD
    const int mL = t / Nt;
    bm = (xcd * 7 + mL) * 256;
    bn = (t - mL * Nt) * 256;
  };

  f32x4 acc[8][4] = {};

  // whole-tile epilogue, ni-outer so bias/rsc/rsh load once per column
  auto epi = [&](int bm, int bn) {
    float bs[4] = {0,0,0,0}, bq[4] = {0,0,0,0};
    #pragma unroll
    for (int ni = 0; ni < 4; ni++) {
      const int c = bn + wn*64 + ni*16 + fr;
      const float bc = bias[c];
      float rs = 0.f, rh = 0.f;
      if constexpr (EPI == 2 || EPI == 4) { rs = rsc[c]; rh = rsh[c]; }
      #pragma unroll
      for (int mi = 0; mi < 8; mi++) {
        const int r0 = bm + wm*128 + (mi>>2)*64 + (mi&3)*16 + fg*4;
        float v[4];
        #pragma unroll
        for (int j = 0; j < 4; j++) v[j] = acc[mi][ni][j] + bc;
        if constexpr (EPI == 1) {
          #pragma unroll
          for (int j = 0; j < 4; j++) v[j] = gelu_t(v[j]);
          const unsigned p01 = cvt_pk_bf16(v[0], v[1]);
          const unsigned p23 = cvt_pk_bf16(v[2], v[3]);
          u16* d = obf + (size_t)r0 * N + c;
          d[0] = (u16)p01; d[N] = (u16)(p01 >> 16);
          d[2*N] = (u16)p23; d[3*N] = (u16)(p23 >> 16);
        } else if constexpr (EPI == 2 || EPI == 4) {
          #pragma unroll
          for (int j = 0; j < 4; j++) {
            const float rv = bf2f(res[(size_t)(r0+j) * N + c]);
            const float y = v[j] + __builtin_fmaf(rs, rv, rh);
            if constexpr (EPI == 4) of32[(size_t)(r0+j) * N + c] = y;
            else                    obf[(size_t)(r0+j) * N + c] = f2bf(y);
            bs[ni] += y; bq[ni] += y * y;
          }
        } else {
          const int which = c / DM;
          const int cc = c - which * DM;
          const int hh = cc >> 6, e = cc & 63;
          const int bb = r0 >> 7, l = r0 & 127;
          const unsigned p01 = cvt_pk_bf16(v[0], v[1]);
          const unsigned p23 = cvt_pk_bf16(v[2], v[3]);
          u16* d = obf + (size_t)which * QSZ + ((size_t)(bb*NH + hh) * SEQ + l) * HD + e;
          d[0] = (u16)p01; d[HD] = (u16)(p01 >> 16);
          d[2*HD] = (u16)p23; d[3*HD] = (u16)(p23 >> 16);
        }
        acc[mi][ni] = (f32x4){0.f, 0.f, 0.f, 0.f};
      }
    }
    if constexpr (EPI == 2 || EPI == 4) {
      const int mIdx = bm >> 8;
      #pragma unroll
      for (int ni = 0; ni < 4; ni++) {
        float s = bs[ni], qq = bq[ni];
        s  += __shfl_xor(s, 16);  s  += __shfl_xor(s, 32);
        qq += __shfl_xor(qq, 16); qq += __shfl_xor(qq, 32);
        if (fg == 0) {
          const int c = bn + wn*64 + ni*16 + fr;
          p1[(mIdx*2 + wm) * N + c] = s;
          p2[(mIdx*2 + wm) * N + c] = qq;
        }
      }
    }
  };

  int r0t = 0, kt0 = 0, bm0, bn0; coord(0, bm0, bn0);
  int r1 = 0, kt1 = 1, bm1 = bm0, bn1 = bn0;
  int r2 = 0, kt2 = 2, bm2 = bm0;
  if (kt2 >= nt) { kt2 -= nt; r2 = 1; int d; if (r2 < TPB) coord(r2, bm2, d); }

  stA2(0, 0, bm0*K); stA2(0, 1, bm0*K);
  stB2(0, 0, bn0*K); stB2(0, 1, bn0*K);
  if (tot > 1) stA2(1, 0, bm1*K + kt1*64);
  asm volatile("s_waitcnt vmcnt(2)" ::: "memory");
  __builtin_amdgcn_s_barrier();

  short8 bk0[4], bk1[4], av[4];
  for (int it = 0; it < tot; ++it) {
    const int bufc = it & 1, nb = bufc ^ 1;
    const bool st1 = (it + 1 < tot), st2 = (it + 2 < tot);
    const int sB1 = bn1*K + kt1*64;
    const int sA1 = bm1*K + kt1*64;
    const int sA2 = bm2*K + kt2*64;
    // ---------------- P1: (mh0, k0) ----------------
    #pragma unroll
    for (int i = 0; i < 4; i++) av[i] = rdA2(bufc, 0, 0, i);
    #pragma unroll
    for (int i = 0; i < 4; i++) bk0[i] = rdB2(bufc, 0, i);
    if (st1) stB2(nb, 0, sB1);
    __builtin_amdgcn_s_barrier();
    asm volatile("s_waitcnt lgkmcnt(0)" ::: "memory");
    __builtin_amdgcn_sched_barrier(0);
    __builtin_amdgcn_s_setprio(1);
    #pragma unroll
    for (int mi = 0; mi < 4; mi++)
      #pragma unroll
      for (int ni = 0; ni < 4; ni++)
        acc[mi][ni] = __builtin_amdgcn_mfma_f32_16x16x32_bf16(av[mi], bk0[ni], acc[mi][ni], 0, 0, 0);
    __builtin_amdgcn_s_setprio(0);
    __builtin_amdgcn_s_barrier();
    // ---------------- P2: (mh0, k1) ----------------
    #pragma unroll
    for (int i = 0; i < 4; i++) av[i] = rdA2(bufc, 0, 1, i);
    #pragma unroll
    for (int i = 0; i < 4; i++) bk1[i] = rdB2(bufc, 1, i);
    if (st1) stB2(nb, 1, sB1);
    __builtin_amdgcn_s_barrier();
    asm volatile("s_waitcnt lgkmcnt(0)" ::: "memory");
    __builtin_amdgcn_sched_barrier(0);
    __builtin_amdgcn_s_setprio(1);
    #pragma unroll
    for (int mi = 0; mi < 4; mi++)
      #pragma unroll
      for (int ni = 0; ni < 4; ni++)
        acc[mi][ni] = __builtin_amdgcn_mfma_f32_16x16x32_bf16(av[mi], bk1[ni], acc[mi][ni], 0, 0, 0);
    __builtin_amdgcn_s_setprio(0);
    if (st1) { asm volatile("s_waitcnt vmcnt(4)" ::: "memory"); }
    else     { asm volatile("s_waitcnt vmcnt(0)" ::: "memory"); }
    __builtin_amdgcn_s_barrier();
    // ---------------- P3: (mh1, k0) ----------------
    #pragma unroll
    for (int i = 0; i < 4; i++) av[i] = rdA2(bufc, 1, 0, i);
    if (st2) stA2(bufc, 0, sA2);
    __builtin_amdgcn_s_barrier();
    asm volatile("s_waitcnt lgkmcnt(0)" ::: "memory");
    __builtin_amdgcn_sched_barrier(0);
    __builtin_amdgcn_s_setprio(1);
    #pragma unroll
    for (int mi = 0; mi < 4; mi++)
      #pragma unroll
      for (int ni = 0; ni < 4; ni++)
        acc[4+mi][ni] = __builtin_amdgcn_mfma_f32_16x16x32_bf16(av[mi], bk0[ni], acc[4+mi][ni], 0, 0, 0);
    __builtin_amdgcn_s_setprio(0);
    __builtin_amdgcn_s_barrier();
    // ---------------- P4: (mh1, k1) ----------------
    #pragma unroll
    for (int i = 0; i < 4; i++) av[i] = rdA2(bufc, 1, 1, i);
    if (st1) stA2(nb, 1, sA1);
    __builtin_amdgcn_s_barrier();
    asm volatile("s_waitcnt lgkmcnt(0)" ::: "memory");
    __builtin_amdgcn_sched_barrier(0);
    __builtin_amdgcn_s_setprio(1);
    #pragma unroll
    for (int mi = 0; mi < 4; mi++)
      #pragma unroll
      for (int ni = 0; ni < 4; ni++)
        acc[4+mi][ni] = __builtin_amdgcn_mfma_f32_16x16x32_bf16(av[mi], bk1[ni], acc[4+mi][ni], 0, 0, 0);
    __builtin_amdgcn_s_setprio(0);
    if (st2)      { asm volatile("s_waitcnt vmcnt(4)" ::: "memory"); }
    else if (st1) { asm volatile("s_waitcnt vmcnt(2)" ::: "memory"); }
    __builtin_amdgcn_s_barrier();
    // tile boundary: whole-tile epilogue AFTER the counted wait + barrier
    if (kt0 == nt - 1) {
      epi(bm0, bn0);
      kt0 = 0; r0t++;
      if (r0t < TPB) coord(r0t, bm0, bn0);
    } else kt0++;
    kt1++; if (kt1 == nt) { kt1 = 0; r1++; if (r1 < TPB) coord(r1, bm1, bn1); }
    kt2++; if (kt2 == nt) { kt2 = 0; r2++; if (r2 < TPB) { int d; coord(r2, bm2, d); } }
  }
}

// ---------------- Attention: one block per (b,h) -----------------------------
__global__ __launch_bounds__(256)
void attn_kernel(const u16* __restrict__ qkvb, const u16* __restrict__ biasT,
                 u16* __restrict__ ab)
{
  const int h = blockIdx.x, b = blockIdx.y;
  const int tid = threadIdx.x, w = tid >> 6, lane = tid & 63;
  const int bh = b * NH + h;
  const u16* qp = qkvb + (size_t)bh * SEQ * HD;
  const u16* kp = qkvb + QSZ + (size_t)bh * SEQ * HD;
  const u16* vp = qkvb + 2 * QSZ + (size_t)bh * SEQ * HD;
  __shared__ __align__(16) u16 vT[HD * 136];
  __shared__ __align__(16) u16 P[SEQ * 136];
  {
    const int s = tid & 127, half = tid >> 7;
    #pragma unroll
    for (int rr = 0; rr < 4; rr++) {
      const int e0 = half * 32 + rr * 8;
      short8 v8 = *(const short8*)&vp[s * HD + e0];
      #pragma unroll
      for (int j = 0; j < 8; j++) vT[(e0 + j) * 136 + s] = (u16)v8[j];
    }
  }
  const int fr = lane & 15, fg = lane >> 4;
  f32x4 sacc[2][8] = {};
  #pragma unroll
  for (int ks = 0; ks < 2; ks++) {
    const int k0 = ks * 32 + fg * 8;
    short8 qf[2], kf[8];
    #pragma unroll
    for (int mi = 0; mi < 2; mi++) qf[mi] = *(const short8*)&qp[(w*32 + mi*16 + fr) * HD + k0];
    #pragma unroll
    for (int ni = 0; ni < 8; ni++) kf[ni] = *(const short8*)&kp[(ni*16 + fr) * HD + k0];
    #pragma unroll
    for (int mi = 0; mi < 2; mi++)
      #pragma unroll
      for (int ni = 0; ni < 8; ni++)
        sacc[mi][ni] = __builtin_amdgcn_mfma_f32_16x16x32_bf16(qf[mi], kf[ni], sacc[mi][ni], 0, 0, 0);
  }
  const u16* bt = biasT + (size_t)bh * SEQ * SEQ;
  #pragma unroll
  for (int mi = 0; mi < 2; mi++) {
    #pragma unroll
    for (int j = 0; j < 4; j++) {
      const int l = w*32 + mi*16 + fg*4 + j;
      float vals[8];
      float mx = -1e30f;
      #pragma unroll
      for (int ni = 0; ni < 8; ni++) {
        vals[ni] = sacc[mi][ni][j] * 0.125f + bf2f(bt[l * SEQ + ni*16 + fr]);
        mx = fmaxf(mx, vals[ni]);
      }
      #pragma unroll
      for (int d = 1; d < 16; d <<= 1) mx = fmaxf(mx, __shfl_xor(mx, d));
      float sum = 0.f;
      #pragma unroll
      for (int ni = 0; ni < 8; ni++) { vals[ni] = __expf(vals[ni] - mx); sum += vals[ni]; }
      #pragma unroll
      for (int d = 1; d < 16; d <<= 1) sum += __shfl_xor(sum, d);
      const float inv = 1.0f / sum;
      #pragma unroll
      for (int ni = 0; ni < 8; ni++) P[l * 136 + ni*16 + fr] = f2bf(vals[ni] * inv);
    }
  }
  __syncthreads();
  f32x4 oacc[2][4] = {};
  #pragma unroll
  for (int ss = 0; ss < 4; ss++) {
    const int s0 = ss * 32 + fg * 8;
    short8 pf[2], vf[4];
    #pragma unroll
    for (int mi = 0; mi < 2; mi++) pf[mi] = *(const short8*)&P[(w*32 + mi*16 + fr) * 136 + s0];
    #pragma unroll
    for (int ei = 0; ei < 4; ei++) vf[ei] = *(const short8*)&vT[(ei*16 + fr) * 136 + s0];
    #pragma unroll
    for (int mi = 0; mi < 2; mi++)
      #pragma unroll
      for (int ei = 0; ei < 4; ei++)
        oacc[mi][ei] = __builtin_amdgcn_mfma_f32_16x16x32_bf16(pf[mi], vf[ei], oacc[mi][ei], 0, 0, 0);
  }
  #pragma unroll
  for (int mi = 0; mi < 2; mi++)
    #pragma unroll
    for (int ei = 0; ei < 4; ei++)
      #pragma unroll
      for (int j = 0; j < 4; j++) {
        const int r = b * SEQ + w*32 + mi*16 + fg*4 + j;
        const int c = h * HD + ei*16 + fr;
        ab[(size_t)r * DM + c] = f2bf(oacc[mi][ei][j]);
      }
}

// ---------------- BatchNorm finalize from fused partials ---------------------
template<bool FINAL>
__global__ __launch_bounds__(256)
void bn_final(const float* __restrict__ p1, const float* __restrict__ p2,
              const float* __restrict__ ga, const float* __restrict__ be,
              const float* __restrict__ gb, const float* __restrict__ beb,
              float* __restrict__ sc, float* __restrict__ sh)
{
  const int c = blockIdx.x * 256 + threadIdx.x;
  float s = 0, q = 0;
  for (int i = 0; i < 112; i++) { s += p1[i * DM + c]; q += p2[i * DM + c]; }
  const float mean = s * (1.0f / MTOK);
  const float var = q * (1.0f / MTOK) - mean * mean;
  const float rstd = rsqrtf(var + 1e-5f);
  if constexpr (!FINAL) {
    const float g = ga[c] * rstd;
    sc[c] = g;
    sh[c] = be[c] - mean * g;
  } else {
    const float sc2 = ga[c] * rstd;
    const float sh2 = be[c] - mean * sc2;
    const float varf = sc2 * sc2 * var;
    const float meanf = sc2 * mean + sh2;
    const float scf = gb[c] * rsqrtf(varf + 1e-5f);
    const float shf = beb[c] - meanf * scf;
    sc[c] = scf * sc2;
    sh[c] = scf * sh2 + shf;
  }
}

__global__ __launch_bounds__(256)
void bn_apply_f32(const float* __restrict__ xi, const float* __restrict__ sc,
                  const float* __restrict__ sh, float* __restrict__ xo)
{
  const int i = blockIdx.x * 256 + threadIdx.x;
  const int cv = i % (DM / 4);
  float4 v = ((const float4*)xi)[i];
  const float4 s = ((const float4*)sc)[cv];
  const float4 h = ((const float4*)sh)[cv];
  float4 y;
  y.x = v.x * s.x + h.x; y.y = v.y * s.y + h.y;
  y.z = v.z * s.z + h.z; y.w = v.w * s.w + h.w;
  ((float4*)xo)[i] = y;
}

// ---------------- BN-fold helpers -------------------------------------------
__global__ __launch_bounds__(256)
void scale_w(const u16* __restrict__ w, const float* __restrict__ sc,
             u16* __restrict__ d, int total8, int K)
{
  const int i = blockIdx.x * 256 + threadIdx.x;
  if (i >= total8) return;
  const int base = i * 8;
  const int col = base % K;
  short8 v = *(const short8*)&w[base];
  const float4 s0 = *(const float4*)&sc[col];
  const float4 s1 = *(const float4*)&sc[col + 4];
  short8 r;
  r[0] = (short)f2bf(bf2f((u16)v[0]) * s0.x);
  r[1] = (short)f2bf(bf2f((u16)v[1]) * s0.y);
  r[2] = (short)f2bf(bf2f((u16)v[2]) * s0.z);
  r[3] = (short)f2bf(bf2f((u16)v[3]) * s0.w);
  r[4] = (short)f2bf(bf2f((u16)v[4]) * s1.x);
  r[5] = (short)f2bf(bf2f((u16)v[5]) * s1.y);
  r[6] = (short)f2bf(bf2f((u16)v[6]) * s1.z);
  r[7] = (short)f2bf(bf2f((u16)v[7]) * s1.w);
  *(short8*)&d[base] = r;
}

// b'[n] = b[n] + sum_k W[n,k]*sh[k]   (wave per row)
__global__ __launch_bounds__(256)
void fold_bias(const u16* __restrict__ w, const float* __restrict__ sh,
               const float* __restrict__ b, float* __restrict__ bout, int N, int K)
{
  const int n = blockIdx.x * 4 + (threadIdx.x >> 6);
  const int lane = threadIdx.x & 63;
  if (n >= N) return;
  float s = 0.f;
  for (int k = lane; k < K; k += 64) s += bf2f(w[(size_t)n * K + k]) * sh[k];
  #pragma unroll
  for (int d = 1; d < 64; d <<= 1) s += __shfl_xor(s, d);
  if (lane == 0) bout[n] = b[n] + s;
}

__global__ __launch_bounds__(256)
void init_affine(float* __restrict__ one, float* __restrict__ zero)
{
  const int i = blockIdx.x * 256 + threadIdx.x;
  if (i < DM) { one[i] = 1.0f; zero[i] = 0.0f; }
}

// ---------------- setup kernels ----------------------------------------------
__global__ __launch_bounds__(256)
void conv_bf16(const float* __restrict__ s, u16* __restrict__ d, int n4)
{
  const int i = blockIdx.x * 256 + threadIdx.x;
  if (i >= n4) return;
  float4 v = ((const float4*)s)[i];
  us4 pk; pk[0] = f2bf(v.x); pk[1] = f2bf(v.y); pk[2] = f2bf(v.z); pk[3] = f2bf(v.w);
  *(us4*)(d + (size_t)i * 4) = pk;
}

__global__ __launch_bounds__(256)
void conv_qkvw(const float* __restrict__ wq, const float* __restrict__ wk,
               const float* __restrict__ wv, u16* __restrict__ d)
{
  const int i = blockIdx.x * 256 + threadIdx.x;
  const int per = QKVN * DM / 4;
  const int l = i / per;
  const int rem = i - l * per;
  const int r = rem / (DM / 4);
  const int cv = rem - r * (DM / 4);
  const float* srcrow;
  if (r < DM)          srcrow = wq + ((size_t)l * DM + r) * DM;
  else if (r < 2 * DM) srcrow = wk + ((size_t)l * DM + (r - DM)) * DM;
  else                 srcrow = wv + ((size_t)l * DM + (r - 2 * DM)) * DM;
  float4 v = ((const float4*)srcrow)[cv];
  us4 pk; pk[0] = f2bf(v.x); pk[1] = f2bf(v.y); pk[2] = f2bf(v.z); pk[3] = f2bf(v.w);
  *(us4*)(d + (size_t)i * 4) = pk;
}

__global__ __launch_bounds__(256)
void conv_bias_qkv(const float* __restrict__ bq, const float* __restrict__ bk,
                   const float* __restrict__ bv, float* __restrict__ d)
{
  const int i = blockIdx.x * 256 + threadIdx.x;
  const int l = i / QKVN;
  const int r = i - l * QKVN;
  float v;
  if (r < DM)          v = bq[l * DM + r];
  else if (r < 2 * DM) v = bk[l * DM + r - DM];
  else                 v = bv[l * DM + r - 2 * DM];
  d[i] = v;
}

__global__ __launch_bounds__(256)
void bias_tr(const float* __restrict__ src, u16* __restrict__ dst)
{
  const int l = blockIdx.x, b = blockIdx.y;
  __shared__ float row[SEQ * NH];
  const float* s = src + ((size_t)b * SEQ + l) * SEQ * NH;
  for (int i = threadIdx.x; i < SEQ * NH; i += 256) row[i] = s[i];
  __syncthreads();
  for (int i = threadIdx.x; i < SEQ * NH; i += 256) {
    const int h = i >> 7, ss = i & 127;
    dst[((size_t)(b * NH + h) * SEQ + l) * SEQ + ss] = f2bf(row[ss * NH + h]);
  }
}

// ---------------- launch -----------------------------------------------------
extern "C" void kernel_launch(void* const* d_in, const int* in_sizes, int n_in,
                              void* d_out, int out_size, void* d_ws, size_t ws_size,
                              hipStream_t stream)
{
  const float* x    = (const float*)d_in[0];
  const float* abia = (const float*)d_in[1];
  const float* Wq   = (const float*)d_in[2];
  const float* bq   = (const float*)d_in[3];
  const float* Wk   = (const float*)d_in[4];
  const float* bk   = (const float*)d_in[5];
  const float* Wv   = (const float*)d_in[6];
  const float* bv   = (const float*)d_in[7];
  const float* Wo   = (const float*)d_in[8];
  const float* bo   = (const float*)d_in[9];
  const float* W1   = (const float*)d_in[10];
  const float* b1   = (const float*)d_in[11];
  const float* W2   = (const float*)d_in[12];
  const float* b2   = (const float*)d_in[13];
  const float* g1   = (const float*)d_in[14];
  const float* be1  = (const float*)d_in[15];
  const float* g2   = (const float*)d_in[16];
  const float* be2  = (const float*)d_in[17];
  const float* gf   = (const float*)d_in[18];
  const float* bef  = (const float*)d_in[19];
  float* out = (float*)d_out;

  char* ws = (char*)d_ws;
  size_t off = 0;
  auto alloc = [&](size_t n) -> char* {
    char* p = ws + off;
    off = (off + n + 255) & ~(size_t)255;
    return p;
  };
  u16*  wqkv  = (u16*)alloc((size_t)3 * QKVN * DM * 2);
  u16*  wo    = (u16*)alloc((size_t)3 * DM * DM * 2);
  u16*  w1    = (u16*)alloc((size_t)3 * FF * DM * 2);
  u16*  w2    = (u16*)alloc((size_t)3 * DM * FF * 2);
  float* bqkv = (float*)alloc((size_t)3 * QKVN * 4);
  u16*  xb    = (u16*)alloc((size_t)MTOK * DM * 2);   // xin / y2 ping
  u16*  xc    = (u16*)alloc((size_t)MTOK * DM * 2);   // y1 (post-attn residual sum)
  u16*  ab    = (u16*)alloc((size_t)MTOK * DM * 2);
  u16*  big   = (u16*)alloc((size_t)MTOK * FF * 2);
  u16*  biasT = (u16*)alloc((size_t)HEADTOT * SEQ * SEQ * 2);
  u16*  wqs   = (u16*)alloc((size_t)QKVN * DM * 2);
  u16*  w1s   = (u16*)alloc((size_t)FF * DM * 2);
  float* bqs  = (float*)alloc(QKVN * 4);
  float* b1s  = (float*)alloc(FF * 4);
  float* p1   = (float*)alloc((size_t)112 * DM * 4);
  float* p2   = (float*)alloc((size_t)112 * DM * 4);
  float* sc1  = (float*)alloc(DM * 4);
  float* sh1  = (float*)alloc(DM * 4);
  float* scP  = (float*)alloc(DM * 4);
  float* shP  = (float*)alloc(DM * 4);
  float* id1  = (float*)alloc(DM * 4);
  float* id0  = (float*)alloc(DM * 4);
  if (off > ws_size) return;

  conv_qkvw<<<5184, 256, 0, stream>>>(Wq, Wk, Wv, wqkv);
  conv_bf16<<<1728, 256, 0, stream>>>(Wo, wo, 3 * DM * DM / 4);
  conv_bf16<<<6912, 256, 0, stream>>>(W1, w1, 3 * FF * DM / 4);
  conv_bf16<<<6912, 256, 0, stream>>>(W2, w2, 3 * DM * FF / 4);
  conv_bias_qkv<<<27, 256, 0, stream>>>(bq, bk, bv, bqkv);
  bias_tr<<<dim3(SEQ, NB), 256, 0, stream>>>(abia, biasT);
  conv_bf16<<<MTOK * DM / 4 / 256, 256, 0, stream>>>(x, xb, MTOK * DM / 4);
  init_affine<<<3, 256, 0, stream>>>(id1, id0);

  auto gemm = [&](int epi, const u16* Ap, const u16* Wp, const float* bp,
                  u16* ob, float* o32, const u16* rs, const float* rscp,
                  const float* rshp, int M, int N, int K) {
    const int Nt = N / 256;
    // per-XCD tiles = 7 m-panels * Nt; TPB=3 when divisible (QKV/FFN1), else 1
    const int perXcd = 7 * Nt;
    const int tpb = (perXcd % 3 == 0 && perXcd >= 9) ? 3 : 1;
    const int grid = (perXcd / tpb) * 8;   // QKV 168, FFN1 224, O/FFN2 168
    if (epi == 1)
      gemm_bt<1><<<grid, 512, 0, stream>>>(Ap, Wp, bp, ob, o32, rs, rscp, rshp, p1, p2, M, N, K, Nt, tpb);
    else if (epi == 2)
      gemm_bt<2><<<grid, 512, 0, stream>>>(Ap, Wp, bp, ob, o32, rs, rscp, rshp, p1, p2, M, N, K, Nt, tpb);
    else if (epi == 3)
      gemm_bt<3><<<grid, 512, 0, stream>>>(Ap, Wp, bp, ob, o32, rs, rscp, rshp, p1, p2, M, N, K, Nt, tpb);
    else
      gemm_bt<4><<<grid, 512, 0, stream>>>(Ap, Wp, bp, ob, o32, rs, rscp, rshp, p1, p2, M, N, K, Nt, tpb);
  };

  const float* scIn = id1;
  const float* shIn = id0;

  for (int l = 0; l < NLAYER; l++) {
    const u16* wqe; const float* bqe;
    if (l == 0) { wqe = wqkv; bqe = bqkv; }
    else {
      scale_w<<<(QKVN*DM/8 + 255)/256, 256, 0, stream>>>(wqkv + (size_t)l*QKVN*DM, scIn, wqs, QKVN*DM/8, DM);
      fold_bias<<<QKVN/4, 256, 0, stream>>>(wqkv + (size_t)l*QKVN*DM, shIn, bqkv + l*QKVN, bqs, QKVN, DM);
      wqe = wqs; bqe = bqs;
    }
    // q,k,v
    gemm(3, xb, wqe, bqe, big, nullptr, nullptr, nullptr, nullptr, MTOK, QKVN, DM);
    attn_kernel<<<dim3(NH, NB), 256, 0, stream>>>(big, biasT, ab);
    // y1 = attn_out*Wo + bo + x(l)   (x(l) = scIn*xb + shIn)
    gemm(2, ab, wo + (size_t)l * DM * DM, bo + l * DM, xc, nullptr, xb, scIn, shIn,
         MTOK, DM, DM);
    bn_final<false><<<3, 256, 0, stream>>>(p1, p2, g1 + l * DM, be1 + l * DM,
                                           nullptr, nullptr, sc1, sh1);
    // fold BN1 into FFN1 weights
    scale_w<<<(FF*DM/8 + 255)/256, 256, 0, stream>>>(w1 + (size_t)l*FF*DM, sc1, w1s, FF*DM/8, DM);
    fold_bias<<<FF/4, 256, 0, stream>>>(w1 + (size_t)l*FF*DM, sh1, b1 + l*FF, b1s, FF, DM);
    gemm(1, xc, w1s, b1s, big, nullptr, nullptr, nullptr, nullptr, MTOK, FF, DM);
    if (l < NLAYER - 1) {
      // y2 = mid*W2 + b2 + BN1(y1); write bf16 into xb (next layer's xin)
      gemm(2, big, w2 + (size_t)l * DM * FF, b2 + l * DM, xb, nullptr, xc, sc1, sh1,
           MTOK, DM, FF);
      bn_final<false><<<3, 256, 0, stream>>>(p1, p2, g2 + l * DM, be2 + l * DM,
                                             nullptr, nullptr, scP, shP);
      scIn = scP; shIn = shP;
    } else {
      gemm(4, big, w2 + (size_t)l * DM * FF, b2 + l * DM, nullptr, out, xc, sc1, sh1,
           MTOK, DM, FF);
      bn_final<true><<<3, 256, 0, stream>>>(p1, p2, g2 + l * DM, be2 + l * DM,
                                            gf, bef, sc1, sh1);
      bn_apply_f32<<<MTOK * DM / 4 / 256, 256, 0, stream>>>(out, sc1, sh1, out);
    }
  }
}

// Round 9
// 1400.704 us; speedup vs baseline: 1.7512x; 1.7512x over previous
//
#include <hip/hip_runtime.h>

#define NB 112
#define SEQ 128
#define DM 768
#define NH 12
#define HD 64
#define FF 3072
#define NLAYER 3
#define MTOK (NB*SEQ)            // 14336
#define QKVN (3*DM)              // 2304
#define HEADTOT (NB*NH)          // 1344
#define QSZ ((size_t)HEADTOT*SEQ*HD)   // 11010048 elems per q/k/v

typedef unsigned short u16;
typedef __attribute__((ext_vector_type(8))) short short8;
typedef __attribute__((ext_vector_type(4))) float f32x4;
typedef __attribute__((ext_vector_type(4))) unsigned short us4;

__device__ __forceinline__ u16 f2bf(float f){
  unsigned u = __builtin_bit_cast(unsigned, f);
  u += 0x7FFFu + ((u >> 16) & 1u);
  return (u16)(u >> 16);
}
__device__ __forceinline__ float bf2f(u16 b){
  unsigned u = ((unsigned)b) << 16;
  return __builtin_bit_cast(float, u);
}
__device__ __forceinline__ unsigned cvt_pk_bf16(float lo, float hi){
  unsigned r;
  asm("v_cvt_pk_bf16_f32 %0, %1, %2" : "=v"(r) : "v"(lo), "v"(hi));
  return r;
}
// tanh-GELU in sigmoid form: 0.5x(1+tanh(z)) == x / (1 + e^{-2z})
__device__ __forceinline__ float gelu_t(float x){
  const float t = -1.5957691216057308f * x * __builtin_fmaf(0.044715f, x*x, 1.0f);
  return __fdividef(x, 1.0f + __expf(t));
}

__device__ __forceinline__ void gl_lds16(const void* g, void* l){
  __builtin_amdgcn_global_load_lds((const __attribute__((address_space(1))) unsigned*)g,
                                   (__attribute__((address_space(3))) unsigned*)l, 16, 0, 0);
}

// ================= persistent 256x256 8-phase GEMM ===========================
// C[m,n] = sum_k A[m,k]*W[n,k]. 512 thr = 8 waves (2M x 4N).
// Persistent: TPB consecutive tiles per block (n-fastest -> A-panel L2 reuse);
// stage pipeline runs across tile boundaries. 4 phases/K-tile, counted vmcnt.
// Epilogue ONLY at end-of-tile after P4's counted wait (r6 lesson: stores
// count against vmcnt; mid-pipeline epilogue stalls the schedule).
// EPI: 1 = gelu(acc+bias)->bf16
//      2 = y=acc+bias+res(bf16) -> bf16 + BN partials   (intermediate)
//      3 = qkv head-scatter bf16
//      4 = y=acc+bias+res(bf16) -> f32 + BN partials    (final layer)
template<int EPI>
__global__ __launch_bounds__(512, 2)
void gemm_bt(const u16* __restrict__ A, const u16* __restrict__ W,
             const float* __restrict__ bias, u16* __restrict__ obf,
             float* __restrict__ of32, const u16* __restrict__ res,
             float* __restrict__ p1, float* __restrict__ p2,
             int M, int N, int K, int Nt, int TPB)
{
  __shared__ __align__(16) char smem[131072];
  const int tid = threadIdx.x;
  const int w = tid >> 6, lane = tid & 63;
  const int wm = w >> 2, wn = w & 3;
  const int fr = lane & 15, fg = lane >> 4;
  const int fko = fg * 8;
  const int grid = gridDim.x;
  const int q8 = grid >> 3, r8 = grid & 7;
  const int xcd = blockIdx.x & 7, pos = blockIdx.x >> 3;
  const int start = xcd < r8 ? xcd * (q8 + 1) : r8 * (q8 + 1) + (xcd - r8) * q8;
  const int swz = start + pos;
  const int nt = K >> 6;
  const int tot = TPB * nt;
  const int l3 = lane >> 3;
  const int k16s = ((lane & 7) ^ l3) * 8;
  int rowAK[2][2], rowBK[2][2];
  #pragma unroll
  for (int mh = 0; mh < 2; mh++)
    #pragma unroll
    for (int j = 0; j < 2; j++)
      rowAK[mh][j] = (mh*64 + j*128 + w*8 + l3) * K;
  #pragma unroll
  for (int h = 0; h < 2; h++)
    #pragma unroll
    for (int j = 0; j < 2; j++)
      rowBK[h][j] = (h*128 + (w + j*8)*8 + l3) * K;

  auto stA2 = [&](int bb, int mh, int soff) {
    const u16* g0 = A + (size_t)soff + rowAK[mh][0] + k16s;
    const u16* g1 = A + (size_t)soff + rowAK[mh][1] + k16s;
    char* d = smem + bb*65536 + (mh*64 + w*8)*128;
    gl_lds16(g0, d);
    gl_lds16(g1, d + 16384);
  };
  auto stB2 = [&](int bb, int h, int soff) {
    const u16* g0 = W + (size_t)soff + rowBK[h][0] + k16s;
    const u16* g1 = W + (size_t)soff + rowBK[h][1] + k16s;
    char* d = smem + bb*65536 + 32768 + (h*128 + w*8)*128;
    gl_lds16(g0, d);
    gl_lds16(g1, d + 8192);
  };
  const int axor = (fr & 7) << 4;
  auto rdA2 = [&](int bb, int mh, int kh, int mf) -> short8 {
    const int row = wm*128 + mh*64 + mf*16 + fr;
    return *(const short8*)(smem + bb*65536 + row*128 + (((kh*32 + fko)*2) ^ axor));
  };
  auto rdB2 = [&](int bb, int kh, int nf) -> short8 {
    const int row = wn*64 + nf*16 + fr;
    return *(const short8*)(smem + bb*65536 + 32768 + row*128 + (((kh*32 + fko)*2) ^ axor));
  };
  auto coord = [&](int r, int& bm, int& bn) {
    const int lin = swz * TPB + r;
    const int mI = lin / Nt;
    bm = mI * 256; bn = (lin - mI * Nt) * 256;
  };

  f32x4 acc[8][4] = {};

  // whole-tile epilogue, ni-outer so bias/scalars load once per column
  auto epi = [&](int bm, int bn) {
    float bs[4] = {0,0,0,0}, bq[4] = {0,0,0,0};
    #pragma unroll
    for (int ni = 0; ni < 4; ni++) {
      const int c = bn + wn*64 + ni*16 + fr;
      const float bc = bias[c];
      #pragma unroll
      for (int mi = 0; mi < 8; mi++) {
        const int r0 = bm + wm*128 + (mi>>2)*64 + (mi&3)*16 + fg*4;
        float v[4];
        #pragma unroll
        for (int j = 0; j < 4; j++) v[j] = acc[mi][ni][j] + bc;
        if constexpr (EPI == 1) {
          #pragma unroll
          for (int j = 0; j < 4; j++) v[j] = gelu_t(v[j]);
          const unsigned p01 = cvt_pk_bf16(v[0], v[1]);
          const unsigned p23 = cvt_pk_bf16(v[2], v[3]);
          u16* d = obf + (size_t)r0 * N + c;
          d[0] = (u16)p01; d[N] = (u16)(p01 >> 16);
          d[2*N] = (u16)p23; d[3*N] = (u16)(p23 >> 16);
        } else if constexpr (EPI == 2 || EPI == 4) {
          #pragma unroll
          for (int j = 0; j < 4; j++) {
            const float y = v[j] + bf2f(res[(size_t)(r0+j) * N + c]);
            if constexpr (EPI == 4) of32[(size_t)(r0+j) * N + c] = y;
            else                    obf[(size_t)(r0+j) * N + c] = f2bf(y);
            bs[ni] += y; bq[ni] += y * y;
          }
        } else {
          const int which = c / DM;
          const int cc = c - which * DM;
          const int hh = cc >> 6, e = cc & 63;
          const int bb = r0 >> 7, l = r0 & 127;
          const unsigned p01 = cvt_pk_bf16(v[0], v[1]);
          const unsigned p23 = cvt_pk_bf16(v[2], v[3]);
          u16* d = obf + (size_t)which * QSZ + ((size_t)(bb*NH + hh) * SEQ + l) * HD + e;
          d[0] = (u16)p01; d[HD] = (u16)(p01 >> 16);
          d[2*HD] = (u16)p23; d[3*HD] = (u16)(p23 >> 16);
        }
        acc[mi][ni] = (f32x4){0.f, 0.f, 0.f, 0.f};
      }
    }
    if constexpr (EPI == 2 || EPI == 4) {
      const int mIdx = bm >> 8;
      #pragma unroll
      for (int ni = 0; ni < 4; ni++) {
        float s = bs[ni], qq = bq[ni];
        s  += __shfl_xor(s, 16);  s  += __shfl_xor(s, 32);
        qq += __shfl_xor(qq, 16); qq += __shfl_xor(qq, 32);
        if (fg == 0) {
          const int c = bn + wn*64 + ni*16 + fr;
          p1[(mIdx*2 + wm) * N + c] = s;
          p2[(mIdx*2 + wm) * N + c] = qq;
        }
      }
    }
  };

  int r0t = 0, kt0 = 0, bm0, bn0; coord(0, bm0, bn0);
  int r1 = 0, kt1 = 1, bm1 = bm0, bn1 = bn0;
  int r2 = 0, kt2 = 2, bm2 = bm0;
  if (kt2 >= nt) { kt2 -= nt; r2 = 1; int d; if (r2 < TPB) coord(r2, bm2, d); }

  stA2(0, 0, bm0*K); stA2(0, 1, bm0*K);
  stB2(0, 0, bn0*K); stB2(0, 1, bn0*K);
  if (tot > 1) stA2(1, 0, bm1*K + kt1*64);
  asm volatile("s_waitcnt vmcnt(2)" ::: "memory");
  __builtin_amdgcn_s_barrier();

  short8 bk0[4], bk1[4], av[4];
  for (int it = 0; it < tot; ++it) {
    const int bufc = it & 1, nb = bufc ^ 1;
    const bool st1 = (it + 1 < tot), st2 = (it + 2 < tot);
    const int sB1 = bn1*K + kt1*64;
    const int sA1 = bm1*K + kt1*64;
    const int sA2 = bm2*K + kt2*64;
    // ---------------- P1: (mh0, k0) ----------------
    #pragma unroll
    for (int i = 0; i < 4; i++) av[i] = rdA2(bufc, 0, 0, i);
    #pragma unroll
    for (int i = 0; i < 4; i++) bk0[i] = rdB2(bufc, 0, i);
    if (st1) stB2(nb, 0, sB1);
    __builtin_amdgcn_s_barrier();
    asm volatile("s_waitcnt lgkmcnt(0)" ::: "memory");
    __builtin_amdgcn_sched_barrier(0);
    __builtin_amdgcn_s_setprio(1);
    #pragma unroll
    for (int mi = 0; mi < 4; mi++)
      #pragma unroll
      for (int ni = 0; ni < 4; ni++)
        acc[mi][ni] = __builtin_amdgcn_mfma_f32_16x16x32_bf16(av[mi], bk0[ni], acc[mi][ni], 0, 0, 0);
    __builtin_amdgcn_s_setprio(0);
    __builtin_amdgcn_s_barrier();
    // ---------------- P2: (mh0, k1) ----------------
    #pragma unroll
    for (int i = 0; i < 4; i++) av[i] = rdA2(bufc, 0, 1, i);
    #pragma unroll
    for (int i = 0; i < 4; i++) bk1[i] = rdB2(bufc, 1, i);
    if (st1) stB2(nb, 1, sB1);
    __builtin_amdgcn_s_barrier();
    asm volatile("s_waitcnt lgkmcnt(0)" ::: "memory");
    __builtin_amdgcn_sched_barrier(0);
    __builtin_amdgcn_s_setprio(1);
    #pragma unroll
    for (int mi = 0; mi < 4; mi++)
      #pragma unroll
      for (int ni = 0; ni < 4; ni++)
        acc[mi][ni] = __builtin_amdgcn_mfma_f32_16x16x32_bf16(av[mi], bk1[ni], acc[mi][ni], 0, 0, 0);
    __builtin_amdgcn_s_setprio(0);
    if (st1) { asm volatile("s_waitcnt vmcnt(4)" ::: "memory"); }
    else     { asm volatile("s_waitcnt vmcnt(0)" ::: "memory"); }
    __builtin_amdgcn_s_barrier();
    // ---------------- P3: (mh1, k0) ----------------
    #pragma unroll
    for (int i = 0; i < 4; i++) av[i] = rdA2(bufc, 1, 0, i);
    if (st2) stA2(bufc, 0, sA2);
    __builtin_amdgcn_s_barrier();
    asm volatile("s_waitcnt lgkmcnt(0)" ::: "memory");
    __builtin_amdgcn_sched_barrier(0);
    __builtin_amdgcn_s_setprio(1);
    #pragma unroll
    for (int mi = 0; mi < 4; mi++)
      #pragma unroll
      for (int ni = 0; ni < 4; ni++)
        acc[4+mi][ni] = __builtin_amdgcn_mfma_f32_16x16x32_bf16(av[mi], bk0[ni], acc[4+mi][ni], 0, 0, 0);
    __builtin_amdgcn_s_setprio(0);
    __builtin_amdgcn_s_barrier();
    // ---------------- P4: (mh1, k1) ----------------
    #pragma unroll
    for (int i = 0; i < 4; i++) av[i] = rdA2(bufc, 1, 1, i);
    if (st1) stA2(nb, 1, sA1);
    __builtin_amdgcn_s_barrier();
    asm volatile("s_waitcnt lgkmcnt(0)" ::: "memory");
    __builtin_amdgcn_sched_barrier(0);
    __builtin_amdgcn_s_setprio(1);
    #pragma unroll
    for (int mi = 0; mi < 4; mi++)
      #pragma unroll
      for (int ni = 0; ni < 4; ni++)
        acc[4+mi][ni] = __builtin_amdgcn_mfma_f32_16x16x32_bf16(av[mi], bk1[ni], acc[4+mi][ni], 0, 0, 0);
    __builtin_amdgcn_s_setprio(0);
    if (st2)      { asm volatile("s_waitcnt vmcnt(4)" ::: "memory"); }
    else if (st1) { asm volatile("s_waitcnt vmcnt(2)" ::: "memory"); }
    __builtin_amdgcn_s_barrier();
    if (kt0 == nt - 1) {
      epi(bm0, bn0);
      kt0 = 0; r0t++;
      if (r0t < TPB) coord(r0t, bm0, bn0);
    } else kt0++;
    kt1++; if (kt1 == nt) { kt1 = 0; r1++; if (r1 < TPB) coord(r1, bm1, bn1); }
    kt2++; if (kt2 == nt) { kt2 = 0; r2++; if (r2 < TPB) { int d; coord(r2, bm2, d); } }
  }
}

// ---------------- Attention: one block per (b,h) -----------------------------
__global__ __launch_bounds__(256)
void attn_kernel(const u16* __restrict__ qkvb, const u16* __restrict__ biasT,
                 u16* __restrict__ ab)
{
  const int h = blockIdx.x, b = blockIdx.y;
  const int tid = threadIdx.x, w = tid >> 6, lane = tid & 63;
  const int bh = b * NH + h;
  const u16* qp = qkvb + (size_t)bh * SEQ * HD;
  const u16* kp = qkvb + QSZ + (size_t)bh * SEQ * HD;
  const u16* vp = qkvb + 2 * QSZ + (size_t)bh * SEQ * HD;
  __shared__ __align__(16) u16 vT[HD * 136];
  __shared__ __align__(16) u16 P[SEQ * 136];
  {
    const int s = tid & 127, half = tid >> 7;
    #pragma unroll
    for (int rr = 0; rr < 4; rr++) {
      const int e0 = half * 32 + rr * 8;
      short8 v8 = *(const short8*)&vp[s * HD + e0];
      #pragma unroll
      for (int j = 0; j < 8; j++) vT[(e0 + j) * 136 + s] = (u16)v8[j];
    }
  }
  const int fr = lane & 15, fg = lane >> 4;
  f32x4 sacc[2][8] = {};
  #pragma unroll
  for (int ks = 0; ks < 2; ks++) {
    const int k0 = ks * 32 + fg * 8;
    short8 qf[2], kf[8];
    #pragma unroll
    for (int mi = 0; mi < 2; mi++) qf[mi] = *(const short8*)&qp[(w*32 + mi*16 + fr) * HD + k0];
    #pragma unroll
    for (int ni = 0; ni < 8; ni++) kf[ni] = *(const short8*)&kp[(ni*16 + fr) * HD + k0];
    #pragma unroll
    for (int mi = 0; mi < 2; mi++)
      #pragma unroll
      for (int ni = 0; ni < 8; ni++)
        sacc[mi][ni] = __builtin_amdgcn_mfma_f32_16x16x32_bf16(qf[mi], kf[ni], sacc[mi][ni], 0, 0, 0);
  }
  const u16* bt = biasT + (size_t)bh * SEQ * SEQ;
  #pragma unroll
  for (int mi = 0; mi < 2; mi++) {
    #pragma unroll
    for (int j = 0; j < 4; j++) {
      const int l = w*32 + mi*16 + fg*4 + j;
      float vals[8];
      float mx = -1e30f;
      #pragma unroll
      for (int ni = 0; ni < 8; ni++) {
        vals[ni] = sacc[mi][ni][j] * 0.125f + bf2f(bt[l * SEQ + ni*16 + fr]);
        mx = fmaxf(mx, vals[ni]);
      }
      #pragma unroll
      for (int d = 1; d < 16; d <<= 1) mx = fmaxf(mx, __shfl_xor(mx, d));
      float sum = 0.f;
      #pragma unroll
      for (int ni = 0; ni < 8; ni++) { vals[ni] = __expf(vals[ni] - mx); sum += vals[ni]; }
      #pragma unroll
      for (int d = 1; d < 16; d <<= 1) sum += __shfl_xor(sum, d);
      const float inv = 1.0f / sum;
      #pragma unroll
      for (int ni = 0; ni < 8; ni++) P[l * 136 + ni*16 + fr] = f2bf(vals[ni] * inv);
    }
  }
  __syncthreads();
  f32x4 oacc[2][4] = {};
  #pragma unroll
  for (int ss = 0; ss < 4; ss++) {
    const int s0 = ss * 32 + fg * 8;
    short8 pf[2], vf[4];
    #pragma unroll
    for (int mi = 0; mi < 2; mi++) pf[mi] = *(const short8*)&P[(w*32 + mi*16 + fr) * 136 + s0];
    #pragma unroll
    for (int ei = 0; ei < 4; ei++) vf[ei] = *(const short8*)&vT[(ei*16 + fr) * 136 + s0];
    #pragma unroll
    for (int mi = 0; mi < 2; mi++)
      #pragma unroll
      for (int ei = 0; ei < 4; ei++)
        oacc[mi][ei] = __builtin_amdgcn_mfma_f32_16x16x32_bf16(pf[mi], vf[ei], oacc[mi][ei], 0, 0, 0);
  }
  #pragma unroll
  for (int mi = 0; mi < 2; mi++)
    #pragma unroll
    for (int ei = 0; ei < 4; ei++)
      #pragma unroll
      for (int j = 0; j < 4; j++) {
        const int r = b * SEQ + w*32 + mi*16 + fg*4 + j;
        const int c = h * HD + ei*16 + fr;
        ab[(size_t)r * DM + c] = f2bf(oacc[mi][ei][j]);
      }
}

// ---------------- BatchNorm finalize from fused partials ---------------------
template<bool FINAL>
__global__ __launch_bounds__(256)
void bn_final(const float* __restrict__ p1, const float* __restrict__ p2,
              const float* __restrict__ ga, const float* __restrict__ be,
              const float* __restrict__ gb, const float* __restrict__ beb,
              float* __restrict__ sc, float* __restrict__ sh)
{
  const int c = blockIdx.x * 256 + threadIdx.x;
  float s = 0, q = 0;
  for (int i = 0; i < 112; i++) { s += p1[i * DM + c]; q += p2[i * DM + c]; }
  const float mean = s * (1.0f / MTOK);
  const float var = q * (1.0f / MTOK) - mean * mean;
  const float rstd = rsqrtf(var + 1e-5f);
  if constexpr (!FINAL) {
    const float g = ga[c] * rstd;
    sc[c] = g;
    sh[c] = be[c] - mean * g;
  } else {
    const float sc2 = ga[c] * rstd;
    const float sh2 = be[c] - mean * sc2;
    const float varf = sc2 * sc2 * var;
    const float meanf = sc2 * mean + sh2;
    const float scf = gb[c] * rsqrtf(varf + 1e-5f);
    const float shf = beb[c] - meanf * scf;
    sc[c] = scf * sc2;
    sh[c] = scf * sh2 + shf;
  }
}

// bf16 in -> bf16 out, 8 elems/thread
__global__ __launch_bounds__(256)
void bn_apply_bf(const u16* __restrict__ xi, const float* __restrict__ sc,
                 const float* __restrict__ sh, u16* __restrict__ xo)
{
  const int i = blockIdx.x * 256 + threadIdx.x;   // 8-elem units, total 1376256
  const int c0 = (i % (DM / 8)) * 8;
  short8 v = *(const short8*)&xi[(size_t)i * 8];
  const float4 s0 = *(const float4*)&sc[c0];
  const float4 s1 = *(const float4*)&sc[c0 + 4];
  const float4 h0 = *(const float4*)&sh[c0];
  const float4 h1 = *(const float4*)&sh[c0 + 4];
  short8 r;
  r[0] = (short)f2bf(__builtin_fmaf(bf2f((u16)v[0]), s0.x, h0.x));
  r[1] = (short)f2bf(__builtin_fmaf(bf2f((u16)v[1]), s0.y, h0.y));
  r[2] = (short)f2bf(__builtin_fmaf(bf2f((u16)v[2]), s0.z, h0.z));
  r[3] = (short)f2bf(__builtin_fmaf(bf2f((u16)v[3]), s0.w, h0.w));
  r[4] = (short)f2bf(__builtin_fmaf(bf2f((u16)v[4]), s1.x, h1.x));
  r[5] = (short)f2bf(__builtin_fmaf(bf2f((u16)v[5]), s1.y, h1.y));
  r[6] = (short)f2bf(__builtin_fmaf(bf2f((u16)v[6]), s1.z, h1.z));
  r[7] = (short)f2bf(__builtin_fmaf(bf2f((u16)v[7]), s1.w, h1.w));
  *(short8*)&xo[(size_t)i * 8] = r;
}

__global__ __launch_bounds__(256)
void bn_apply_f32(const float* __restrict__ xi, const float* __restrict__ sc,
                  const float* __restrict__ sh, float* __restrict__ xo)
{
  const int i = blockIdx.x * 256 + threadIdx.x;
  const int cv = i % (DM / 4);
  float4 v = ((const float4*)xi)[i];
  const float4 s = ((const float4*)sc)[cv];
  const float4 h = ((const float4*)sh)[cv];
  float4 y;
  y.x = v.x * s.x + h.x; y.y = v.y * s.y + h.y;
  y.z = v.z * s.z + h.z; y.w = v.w * s.w + h.w;
  ((float4*)xo)[i] = y;
}

// ---------------- setup kernels ----------------------------------------------
__global__ __launch_bounds__(256)
void conv_bf16(const float* __restrict__ s, u16* __restrict__ d, int n4)
{
  const int i = blockIdx.x * 256 + threadIdx.x;
  if (i >= n4) return;
  float4 v = ((const float4*)s)[i];
  us4 pk; pk[0] = f2bf(v.x); pk[1] = f2bf(v.y); pk[2] = f2bf(v.z); pk[3] = f2bf(v.w);
  *(us4*)(d + (size_t)i * 4) = pk;
}

__global__ __launch_bounds__(256)
void conv_qkvw(const float* __restrict__ wq, const float* __restrict__ wk,
               const float* __restrict__ wv, u16* __restrict__ d)
{
  const int i = blockIdx.x * 256 + threadIdx.x;
  const int per = QKVN * DM / 4;
  const int l = i / per;
  const int rem = i - l * per;
  const int r = rem / (DM / 4);
  const int cv = rem - r * (DM / 4);
  const float* srcrow;
  if (r < DM)          srcrow = wq + ((size_t)l * DM + r) * DM;
  else if (r < 2 * DM) srcrow = wk + ((size_t)l * DM + (r - DM)) * DM;
  else                 srcrow = wv + ((size_t)l * DM + (r - 2 * DM)) * DM;
  float4 v = ((const float4*)srcrow)[cv];
  us4 pk; pk[0] = f2bf(v.x); pk[1] = f2bf(v.y); pk[2] = f2bf(v.z); pk[3] = f2bf(v.w);
  *(us4*)(d + (size_t)i * 4) = pk;
}

__global__ __launch_bounds__(256)
void conv_bias_qkv(const float* __restrict__ bq, const float* __restrict__ bk,
                   const float* __restrict__ bv, float* __restrict__ d)
{
  const int i = blockIdx.x * 256 + threadIdx.x;
  const int l = i / QKVN;
  const int r = i - l * QKVN;
  float v;
  if (r < DM)          v = bq[l * DM + r];
  else if (r < 2 * DM) v = bk[l * DM + r - DM];
  else                 v = bv[l * DM + r - 2 * DM];
  d[i] = v;
}

__global__ __launch_bounds__(256)
void bias_tr(const float* __restrict__ src, u16* __restrict__ dst)
{
  const int l = blockIdx.x, b = blockIdx.y;
  __shared__ float row[SEQ * NH];
  const float* s = src + ((size_t)b * SEQ + l) * SEQ * NH;
  for (int i = threadIdx.x; i < SEQ * NH; i += 256) row[i] = s[i];
  __syncthreads();
  for (int i = threadIdx.x; i < SEQ * NH; i += 256) {
    const int h = i >> 7, ss = i & 127;
    dst[((size_t)(b * NH + h) * SEQ + l) * SEQ + ss] = f2bf(row[ss * NH + h]);
  }
}

// ---------------- launch -----------------------------------------------------
extern "C" void kernel_launch(void* const* d_in, const int* in_sizes, int n_in,
                              void* d_out, int out_size, void* d_ws, size_t ws_size,
                              hipStream_t stream)
{
  const float* x    = (const float*)d_in[0];
  const float* abia = (const float*)d_in[1];
  const float* Wq   = (const float*)d_in[2];
  const float* bq   = (const float*)d_in[3];
  const float* Wk   = (const float*)d_in[4];
  const float* bk   = (const float*)d_in[5];
  const float* Wv   = (const float*)d_in[6];
  const float* bv   = (const float*)d_in[7];
  const float* Wo   = (const float*)d_in[8];
  const float* bo   = (const float*)d_in[9];
  const float* W1   = (const float*)d_in[10];
  const float* b1   = (const float*)d_in[11];
  const float* W2   = (const float*)d_in[12];
  const float* b2   = (const float*)d_in[13];
  const float* g1   = (const float*)d_in[14];
  const float* be1  = (const float*)d_in[15];
  const float* g2   = (const float*)d_in[16];
  const float* be2  = (const float*)d_in[17];
  const float* gf   = (const float*)d_in[18];
  const float* bef  = (const float*)d_in[19];
  float* out = (float*)d_out;

  char* ws = (char*)d_ws;
  size_t off = 0;
  auto alloc = [&](size_t n) -> char* {
    char* p = ws + off;
    off = (off + n + 255) & ~(size_t)255;
    return p;
  };
  u16*  wqkv  = (u16*)alloc((size_t)3 * QKVN * DM * 2);
  u16*  wo    = (u16*)alloc((size_t)3 * DM * DM * 2);
  u16*  w1    = (u16*)alloc((size_t)3 * FF * DM * 2);
  u16*  w2    = (u16*)alloc((size_t)3 * DM * FF * 2);
  float* bqkv = (float*)alloc((size_t)3 * QKVN * 4);
  u16*  xb    = (u16*)alloc((size_t)MTOK * DM * 2);   // x (BN'd), bf16
  u16*  yb    = (u16*)alloc((size_t)MTOK * DM * 2);   // raw y (pre-BN), bf16
  u16*  ab    = (u16*)alloc((size_t)MTOK * DM * 2);
  u16*  big   = (u16*)alloc((size_t)MTOK * FF * 2);
  u16*  biasT = (u16*)alloc((size_t)HEADTOT * SEQ * SEQ * 2);
  float* p1   = (float*)alloc((size_t)112 * DM * 4);
  float* p2   = (float*)alloc((size_t)112 * DM * 4);
  float* sc1  = (float*)alloc(DM * 4);
  float* sh1  = (float*)alloc(DM * 4);
  if (off > ws_size) return;

  conv_qkvw<<<5184, 256, 0, stream>>>(Wq, Wk, Wv, wqkv);
  conv_bf16<<<1728, 256, 0, stream>>>(Wo, wo, 3 * DM * DM / 4);
  conv_bf16<<<6912, 256, 0, stream>>>(W1, w1, 3 * FF * DM / 4);
  conv_bf16<<<6912, 256, 0, stream>>>(W2, w2, 3 * DM * FF / 4);
  conv_bias_qkv<<<27, 256, 0, stream>>>(bq, bk, bv, bqkv);
  bias_tr<<<dim3(SEQ, NB), 256, 0, stream>>>(abia, biasT);
  conv_bf16<<<MTOK * DM / 4 / 256, 256, 0, stream>>>(x, xb, MTOK * DM / 4);

  auto gemm = [&](int epi, const u16* Ap, const u16* Wp, const float* bp,
                  u16* ob, float* o32, const u16* rs, int M, int N, int K) {
    const int Nt = N / 256;
    const int tiles = (M / 256) * Nt;
    const int tpb = (tiles + 255) / 256;
    const int grid = tiles / tpb;          // QKV 252, FFN1 224, O/FFN2 168
    if (epi == 1)
      gemm_bt<1><<<grid, 512, 0, stream>>>(Ap, Wp, bp, ob, o32, rs, p1, p2, M, N, K, Nt, tpb);
    else if (epi == 2)
      gemm_bt<2><<<grid, 512, 0, stream>>>(Ap, Wp, bp, ob, o32, rs, p1, p2, M, N, K, Nt, tpb);
    else if (epi == 3)
      gemm_bt<3><<<grid, 512, 0, stream>>>(Ap, Wp, bp, ob, o32, rs, p1, p2, M, N, K, Nt, tpb);
    else
      gemm_bt<4><<<grid, 512, 0, stream>>>(Ap, Wp, bp, ob, o32, rs, p1, p2, M, N, K, Nt, tpb);
  };

  for (int l = 0; l < NLAYER; l++) {
    gemm(3, xb, wqkv + (size_t)l * QKVN * DM, bqkv + l * QKVN, big, nullptr, nullptr,
         MTOK, QKVN, DM);
    attn_kernel<<<dim3(NH, NB), 256, 0, stream>>>(big, biasT, ab);
    // y1 = attn_out*Wo + bo + x   -> bf16 yb + BN partials
    gemm(2, ab, wo + (size_t)l * DM * DM, bo + l * DM, yb, nullptr, xb,
         MTOK, DM, DM);
    bn_final<false><<<3, 256, 0, stream>>>(p1, p2, g1 + l * DM, be1 + l * DM,
                                           nullptr, nullptr, sc1, sh1);
    bn_apply_bf<<<MTOK * DM / 8 / 256, 256, 0, stream>>>(yb, sc1, sh1, xb);
    gemm(1, xb, w1 + (size_t)l * FF * DM, b1 + l * FF, big, nullptr, nullptr,
         MTOK, FF, DM);
    if (l < NLAYER - 1) {
      // y2 = mid*W2 + b2 + x   -> bf16 yb + BN partials
      gemm(2, big, w2 + (size_t)l * DM * FF, b2 + l * DM, yb, nullptr, xb,
           MTOK, DM, FF);
      bn_final<false><<<3, 256, 0, stream>>>(p1, p2, g2 + l * DM, be2 + l * DM,
                                             nullptr, nullptr, sc1, sh1);
      bn_apply_bf<<<MTOK * DM / 8 / 256, 256, 0, stream>>>(yb, sc1, sh1, xb);
    } else {
      gemm(4, big, w2 + (size_t)l * DM * FF, b2 + l * DM, nullptr, out, xb,
           MTOK, DM, FF);
      bn_final<true><<<3, 256, 0, stream>>>(p1, p2, g2 + l * DM, be2 + l * DM,
                                            gf, bef, sc1, sh1);
      bn_apply_f32<<<MTOK * DM / 4 / 256, 256, 0, stream>>>(out, sc1, sh1, out);
    }
  }
}

// Round 10
// 1170.385 us; speedup vs baseline: 2.0959x; 1.1968x over previous
//
#include <hip/hip_runtime.h>

#define NB 112
#define SEQ 128
#define DM 768
#define NH 12
#define HD 64
#define FF 3072
#define NLAYER 3
#define MTOK (NB*SEQ)            // 14336
#define QKVN (3*DM)              // 2304
#define HEADTOT (NB*NH)          // 1344
#define QSZ ((size_t)HEADTOT*SEQ*HD)   // 11010048 elems per q/k/v

typedef unsigned short u16;
typedef __attribute__((ext_vector_type(8))) short short8;
typedef __attribute__((ext_vector_type(4))) float f32x4;
typedef __attribute__((ext_vector_type(4))) unsigned short us4;

__device__ __forceinline__ u16 f2bf(float f){
  unsigned u = __builtin_bit_cast(unsigned, f);
  u += 0x7FFFu + ((u >> 16) & 1u);
  return (u16)(u >> 16);
}
__device__ __forceinline__ float bf2f(u16 b){
  unsigned u = ((unsigned)b) << 16;
  return __builtin_bit_cast(float, u);
}
// packed RNE f32x2 -> bf16x2 (lo=s0, hi=s1)
__device__ __forceinline__ unsigned cvt_pk_bf16(float lo, float hi){
  unsigned r;
  asm("v_cvt_pk_bf16_f32 %0, %1, %2" : "=v"(r) : "v"(lo), "v"(hi));
  return r;
}
// tanh-GELU in sigmoid form: 0.5x(1+tanh(z)) == x / (1 + e^{-2z})
__device__ __forceinline__ float gelu_t(float x){
  const float t = -1.5957691216057308f * x * __builtin_fmaf(0.044715f, x*x, 1.0f);
  return __fdividef(x, 1.0f + __expf(t));
}

__device__ __forceinline__ void gl_lds16(const void* g, void* l){
  __builtin_amdgcn_global_load_lds((const __attribute__((address_space(1))) unsigned*)g,
                                   (__attribute__((address_space(3))) unsigned*)l, 16, 0, 0);
}

// ================= persistent 256x256 8-phase GEMM ===========================
// C[m,n] = sum_k A[m,k]*W[n,k]. 512 thr = 8 waves (2M x 4N).
// Persistent: TPB consecutive tiles per block (n-fastest -> A-panel L2 reuse);
// stage pipeline runs across tile boundaries. 4 phases/K-tile, counted vmcnt.
// EPI: 1 = gelu(acc+bias)->bf16 ; 2 = y=acc+bias+res(bf16) -> f32 + BN partials ;
//      3 = qkv head-scatter bf16
template<int EPI>
__global__ __launch_bounds__(512, 2)
void gemm_bt(const u16* __restrict__ A, const u16* __restrict__ W,
             const float* __restrict__ bias, u16* __restrict__ obf,
             float* __restrict__ of32, const u16* __restrict__ res,
             float* __restrict__ p1, float* __restrict__ p2,
             int M, int N, int K, int Nt, int TPB)
{
  __shared__ __align__(16) char smem[131072];
  const int tid = threadIdx.x;
  const int w = tid >> 6, lane = tid & 63;
  const int wm = w >> 2, wn = w & 3;
  const int fr = lane & 15, fg = lane >> 4;
  const int fko = fg * 8;
  const int grid = gridDim.x;
  const int q8 = grid >> 3, r8 = grid & 7;
  const int xcd = blockIdx.x & 7, pos = blockIdx.x >> 3;
  const int start = xcd < r8 ? xcd * (q8 + 1) : r8 * (q8 + 1) + (xcd - r8) * q8;
  const int swz = start + pos;
  const int nt = K >> 6;
  const int tot = TPB * nt;
  const int l3 = lane >> 3;
  const int k16s = ((lane & 7) ^ l3) * 8;
  int rowAK[2][2], rowBK[2][2];
  #pragma unroll
  for (int mh = 0; mh < 2; mh++)
    #pragma unroll
    for (int j = 0; j < 2; j++)
      rowAK[mh][j] = (mh*64 + j*128 + w*8 + l3) * K;
  #pragma unroll
  for (int h = 0; h < 2; h++)
    #pragma unroll
    for (int j = 0; j < 2; j++)
      rowBK[h][j] = (h*128 + (w + j*8)*8 + l3) * K;

  auto stA2 = [&](int bb, int mh, int soff) {
    const u16* g0 = A + (size_t)soff + rowAK[mh][0] + k16s;
    const u16* g1 = A + (size_t)soff + rowAK[mh][1] + k16s;
    char* d = smem + bb*65536 + (mh*64 + w*8)*128;
    gl_lds16(g0, d);
    gl_lds16(g1, d + 16384);
  };
  auto stB2 = [&](int bb, int h, int soff) {
    const u16* g0 = W + (size_t)soff + rowBK[h][0] + k16s;
    const u16* g1 = W + (size_t)soff + rowBK[h][1] + k16s;
    char* d = smem + bb*65536 + 32768 + (h*128 + w*8)*128;
    gl_lds16(g0, d);
    gl_lds16(g1, d + 8192);
  };
  const int axor = (fr & 7) << 4;
  auto rdA2 = [&](int bb, int mh, int kh, int mf) -> short8 {
    const int row = wm*128 + mh*64 + mf*16 + fr;
    return *(const short8*)(smem + bb*65536 + row*128 + (((kh*32 + fko)*2) ^ axor));
  };
  auto rdB2 = [&](int bb, int kh, int nf) -> short8 {
    const int row = wn*64 + nf*16 + fr;
    return *(const short8*)(smem + bb*65536 + 32768 + row*128 + (((kh*32 + fko)*2) ^ axor));
  };
  auto coord = [&](int r, int& bm, int& bn) {
    const int lin = swz * TPB + r;
    const int mI = lin / Nt;
    bm = mI * 256; bn = (lin - mI * Nt) * 256;
  };

  f32x4 acc[8][4] = {};

  auto epi = [&](int bm, int bn) {
    float bs[4] = {0,0,0,0}, bq[4] = {0,0,0,0};
    #pragma unroll
    for (int mi = 0; mi < 8; mi++) {
      #pragma unroll
      for (int ni = 0; ni < 4; ni++) {
        const int c = bn + wn*64 + ni*16 + fr;
        const int r0 = bm + wm*128 + (mi>>2)*64 + (mi&3)*16 + fg*4;
        const float bc = bias[c];
        float v[4];
        #pragma unroll
        for (int j = 0; j < 4; j++) v[j] = acc[mi][ni][j] + bc;
        if constexpr (EPI == 1) {
          #pragma unroll
          for (int j = 0; j < 4; j++) v[j] = gelu_t(v[j]);
          const unsigned p01 = cvt_pk_bf16(v[0], v[1]);
          const unsigned p23 = cvt_pk_bf16(v[2], v[3]);
          u16* d = obf + (size_t)r0 * N + c;
          d[0] = (u16)p01; d[N] = (u16)(p01 >> 16);
          d[2*N] = (u16)p23; d[3*N] = (u16)(p23 >> 16);
        } else if constexpr (EPI == 2) {
          #pragma unroll
          for (int j = 0; j < 4; j++) {
            const float y = v[j] + bf2f(res[(size_t)(r0+j) * N + c]);
            of32[(size_t)(r0+j) * N + c] = y;
            bs[ni] += y; bq[ni] += y * y;
          }
        } else {
          const int which = c / DM;
          const int cc = c - which * DM;
          const int hh = cc >> 6, e = cc & 63;
          const int bb = r0 >> 7, l = r0 & 127;
          const unsigned p01 = cvt_pk_bf16(v[0], v[1]);
          const unsigned p23 = cvt_pk_bf16(v[2], v[3]);
          u16* d = obf + (size_t)which * QSZ + ((size_t)(bb*NH + hh) * SEQ + l) * HD + e;
          d[0] = (u16)p01; d[HD] = (u16)(p01 >> 16);
          d[2*HD] = (u16)p23; d[3*HD] = (u16)(p23 >> 16);
        }
        acc[mi][ni] = (f32x4){0.f, 0.f, 0.f, 0.f};
      }
    }
    if constexpr (EPI == 2) {
      const int mIdx = bm >> 8;
      #pragma unroll
      for (int ni = 0; ni < 4; ni++) {
        float s = bs[ni], qq = bq[ni];
        s  += __shfl_xor(s, 16);  s  += __shfl_xor(s, 32);
        qq += __shfl_xor(qq, 16); qq += __shfl_xor(qq, 32);
        if (fg == 0) {
          const int c = bn + wn*64 + ni*16 + fr;
          p1[(mIdx*2 + wm) * N + c] = s;
          p2[(mIdx*2 + wm) * N + c] = qq;
        }
      }
    }
  };

  int r0t = 0, kt0 = 0, bm0, bn0; coord(0, bm0, bn0);
  int r1 = 0, kt1 = 1, bm1 = bm0, bn1 = bn0;
  int r2 = 0, kt2 = 2, bm2 = bm0;
  if (kt2 >= nt) { kt2 -= nt; r2 = 1; int d; if (r2 < TPB) coord(r2, bm2, d); }

  stA2(0, 0, bm0*K); stA2(0, 1, bm0*K);
  stB2(0, 0, bn0*K); stB2(0, 1, bn0*K);
  if (tot > 1) stA2(1, 0, bm1*K + kt1*64);
  asm volatile("s_waitcnt vmcnt(2)" ::: "memory");
  __builtin_amdgcn_s_barrier();

  short8 bk0[4], bk1[4], av[4];
  for (int it = 0; it < tot; ++it) {
    const int bufc = it & 1, nb = bufc ^ 1;
    const bool st1 = (it + 1 < tot), st2 = (it + 2 < tot);
    const int sB1 = bn1*K + kt1*64;
    const int sA1 = bm1*K + kt1*64;
    const int sA2 = bm2*K + kt2*64;
    // ---------------- P1: (mh0, k0) ----------------
    #pragma unroll
    for (int i = 0; i < 4; i++) av[i] = rdA2(bufc, 0, 0, i);
    #pragma unroll
    for (int i = 0; i < 4; i++) bk0[i] = rdB2(bufc, 0, i);
    if (st1) stB2(nb, 0, sB1);
    __builtin_amdgcn_s_barrier();
    asm volatile("s_waitcnt lgkmcnt(0)" ::: "memory");
    __builtin_amdgcn_sched_barrier(0);
    __builtin_amdgcn_s_setprio(1);
    #pragma unroll
    for (int mi = 0; mi < 4; mi++)
      #pragma unroll
      for (int ni = 0; ni < 4; ni++)
        acc[mi][ni] = __builtin_amdgcn_mfma_f32_16x16x32_bf16(av[mi], bk0[ni], acc[mi][ni], 0, 0, 0);
    __builtin_amdgcn_s_setprio(0);
    __builtin_amdgcn_s_barrier();
    // ---------------- P2: (mh0, k1) ----------------
    #pragma unroll
    for (int i = 0; i < 4; i++) av[i] = rdA2(bufc, 0, 1, i);
    #pragma unroll
    for (int i = 0; i < 4; i++) bk1[i] = rdB2(bufc, 1, i);
    if (st1) stB2(nb, 1, sB1);
    __builtin_amdgcn_s_barrier();
    asm volatile("s_waitcnt lgkmcnt(0)" ::: "memory");
    __builtin_amdgcn_sched_barrier(0);
    __builtin_amdgcn_s_setprio(1);
    #pragma unroll
    for (int mi = 0; mi < 4; mi++)
      #pragma unroll
      for (int ni = 0; ni < 4; ni++)
        acc[mi][ni] = __builtin_amdgcn_mfma_f32_16x16x32_bf16(av[mi], bk1[ni], acc[mi][ni], 0, 0, 0);
    __builtin_amdgcn_s_setprio(0);
    if (st1) { asm volatile("s_waitcnt vmcnt(4)" ::: "memory"); }
    else     { asm volatile("s_waitcnt vmcnt(0)" ::: "memory"); }
    __builtin_amdgcn_s_barrier();
    // ---------------- P3: (mh1, k0) ----------------
    #pragma unroll
    for (int i = 0; i < 4; i++) av[i] = rdA2(bufc, 1, 0, i);
    if (st2) stA2(bufc, 0, sA2);
    __builtin_amdgcn_s_barrier();
    asm volatile("s_waitcnt lgkmcnt(0)" ::: "memory");
    __builtin_amdgcn_sched_barrier(0);
    __builtin_amdgcn_s_setprio(1);
    #pragma unroll
    for (int mi = 0; mi < 4; mi++)
      #pragma unroll
      for (int ni = 0; ni < 4; ni++)
        acc[4+mi][ni] = __builtin_amdgcn_mfma_f32_16x16x32_bf16(av[mi], bk0[ni], acc[4+mi][ni], 0, 0, 0);
    __builtin_amdgcn_s_setprio(0);
    __builtin_amdgcn_s_barrier();
    // ---------------- P4: (mh1, k1) ----------------
    #pragma unroll
    for (int i = 0; i < 4; i++) av[i] = rdA2(bufc, 1, 1, i);
    if (st1) stA2(nb, 1, sA1);
    __builtin_amdgcn_s_barrier();
    asm volatile("s_waitcnt lgkmcnt(0)" ::: "memory");
    __builtin_amdgcn_sched_barrier(0);
    __builtin_amdgcn_s_setprio(1);
    #pragma unroll
    for (int mi = 0; mi < 4; mi++)
      #pragma unroll
      for (int ni = 0; ni < 4; ni++)
        acc[4+mi][ni] = __builtin_amdgcn_mfma_f32_16x16x32_bf16(av[mi], bk1[ni], acc[4+mi][ni], 0, 0, 0);
    __builtin_amdgcn_s_setprio(0);
    if (st2)      { asm volatile("s_waitcnt vmcnt(4)" ::: "memory"); }
    else if (st1) { asm volatile("s_waitcnt vmcnt(2)" ::: "memory"); }
    __builtin_amdgcn_s_barrier();
    if (kt0 == nt - 1) {
      epi(bm0, bn0);
      kt0 = 0; r0t++;
      if (r0t < TPB) coord(r0t, bm0, bn0);
    } else kt0++;
    kt1++; if (kt1 == nt) { kt1 = 0; r1++; if (r1 < TPB) coord(r1, bm1, bn1); }
    kt2++; if (kt2 == nt) { kt2 = 0; r2++; if (r2 < TPB) { int d; coord(r2, bm2, d); } }
  }
}

// ---------------- Attention: one block per (b,h) -----------------------------
__global__ __launch_bounds__(256)
void attn_kernel(const u16* __restrict__ qkvb, const u16* __restrict__ biasT,
                 u16* __restrict__ ab)
{
  const int h = blockIdx.x, b = blockIdx.y;
  const int tid = threadIdx.x, w = tid >> 6, lane = tid & 63;
  const int bh = b * NH + h;
  const u16* qp = qkvb + (size_t)bh * SEQ * HD;
  const u16* kp = qkvb + QSZ + (size_t)bh * SEQ * HD;
  const u16* vp = qkvb + 2 * QSZ + (size_t)bh * SEQ * HD;
  __shared__ __align__(16) u16 vT[HD * 136];
  __shared__ __align__(16) u16 P[SEQ * 136];
  {
    const int s = tid & 127, half = tid >> 7;
    #pragma unroll
    for (int rr = 0; rr < 4; rr++) {
      const int e0 = half * 32 + rr * 8;
      short8 v8 = *(const short8*)&vp[s * HD + e0];
      #pragma unroll
      for (int j = 0; j < 8; j++) vT[(e0 + j) * 136 + s] = (u16)v8[j];
    }
  }
  const int fr = lane & 15, fg = lane >> 4;
  f32x4 sacc[2][8] = {};
  #pragma unroll
  for (int ks = 0; ks < 2; ks++) {
    const int k0 = ks * 32 + fg * 8;
    short8 qf[2], kf[8];
    #pragma unroll
    for (int mi = 0; mi < 2; mi++) qf[mi] = *(const short8*)&qp[(w*32 + mi*16 + fr) * HD + k0];
    #pragma unroll
    for (int ni = 0; ni < 8; ni++) kf[ni] = *(const short8*)&kp[(ni*16 + fr) * HD + k0];
    #pragma unroll
    for (int mi = 0; mi < 2; mi++)
      #pragma unroll
      for (int ni = 0; ni < 8; ni++)
        sacc[mi][ni] = __builtin_amdgcn_mfma_f32_16x16x32_bf16(qf[mi], kf[ni], sacc[mi][ni], 0, 0, 0);
  }
  const u16* bt = biasT + (size_t)bh * SEQ * SEQ;
  #pragma unroll
  for (int mi = 0; mi < 2; mi++) {
    #pragma unroll
    for (int j = 0; j < 4; j++) {
      const int l = w*32 + mi*16 + fg*4 + j;
      float vals[8];
      float mx = -1e30f;
      #pragma unroll
      for (int ni = 0; ni < 8; ni++) {
        vals[ni] = sacc[mi][ni][j] * 0.125f + bf2f(bt[l * SEQ + ni*16 + fr]);
        mx = fmaxf(mx, vals[ni]);
      }
      #pragma unroll
      for (int d = 1; d < 16; d <<= 1) mx = fmaxf(mx, __shfl_xor(mx, d));
      float sum = 0.f;
      #pragma unroll
      for (int ni = 0; ni < 8; ni++) { vals[ni] = __expf(vals[ni] - mx); sum += vals[ni]; }
      #pragma unroll
      for (int d = 1; d < 16; d <<= 1) sum += __shfl_xor(sum, d);
      const float inv = 1.0f / sum;
      #pragma unroll
      for (int ni = 0; ni < 8; ni++) P[l * 136 + ni*16 + fr] = f2bf(vals[ni] * inv);
    }
  }
  __syncthreads();
  f32x4 oacc[2][4] = {};
  #pragma unroll
  for (int ss = 0; ss < 4; ss++) {
    const int s0 = ss * 32 + fg * 8;
    short8 pf[2], vf[4];
    #pragma unroll
    for (int mi = 0; mi < 2; mi++) pf[mi] = *(const short8*)&P[(w*32 + mi*16 + fr) * 136 + s0];
    #pragma unroll
    for (int ei = 0; ei < 4; ei++) vf[ei] = *(const short8*)&vT[(ei*16 + fr) * 136 + s0];
    #pragma unroll
    for (int mi = 0; mi < 2; mi++)
      #pragma unroll
      for (int ei = 0; ei < 4; ei++)
        oacc[mi][ei] = __builtin_amdgcn_mfma_f32_16x16x32_bf16(pf[mi], vf[ei], oacc[mi][ei], 0, 0, 0);
  }
  #pragma unroll
  for (int mi = 0; mi < 2; mi++)
    #pragma unroll
    for (int ei = 0; ei < 4; ei++)
      #pragma unroll
      for (int j = 0; j < 4; j++) {
        const int r = b * SEQ + w*32 + mi*16 + fg*4 + j;
        const int c = h * HD + ei*16 + fr;
        ab[(size_t)r * DM + c] = f2bf(oacc[mi][ei][j]);
      }
}

// ---------------- BatchNorm finalize from fused partials ---------------------
template<bool FINAL>
__global__ __launch_bounds__(256)
void bn_final(const float* __restrict__ p1, const float* __restrict__ p2,
              const float* __restrict__ ga, const float* __restrict__ be,
              const float* __restrict__ gb, const float* __restrict__ beb,
              float* __restrict__ sc, float* __restrict__ sh)
{
  const int c = blockIdx.x * 256 + threadIdx.x;
  float s = 0, q = 0;
  for (int i = 0; i < 112; i++) { s += p1[i * DM + c]; q += p2[i * DM + c]; }
  const float mean = s * (1.0f / MTOK);
  const float var = q * (1.0f / MTOK) - mean * mean;
  const float rstd = rsqrtf(var + 1e-5f);
  if constexpr (!FINAL) {
    const float g = ga[c] * rstd;
    sc[c] = g;
    sh[c] = be[c] - mean * g;
  } else {
    const float sc2 = ga[c] * rstd;
    const float sh2 = be[c] - mean * sc2;
    const float varf = sc2 * sc2 * var;
    const float meanf = sc2 * mean + sh2;
    const float scf = gb[c] * rsqrtf(varf + 1e-5f);
    const float shf = beb[c] - meanf * scf;
    sc[c] = scf * sc2;
    sh[c] = scf * sh2 + shf;
  }
}

// MODE 0: write xb (bf16) only (intermediate); MODE 1: write out f32 (final)
template<int MODE>
__global__ __launch_bounds__(256)
void bn_apply(const float* __restrict__ xi, const float* __restrict__ sc,
              const float* __restrict__ sh, float* __restrict__ xo, u16* __restrict__ xb)
{
  const int i = blockIdx.x * 256 + threadIdx.x;
  const int cv = i % (DM / 4);
  float4 v = ((const float4*)xi)[i];
  const float4 s = ((const float4*)sc)[cv];
  const float4 h = ((const float4*)sh)[cv];
  float4 y;
  y.x = v.x * s.x + h.x; y.y = v.y * s.y + h.y;
  y.z = v.z * s.z + h.z; y.w = v.w * s.w + h.w;
  if constexpr (MODE == 1) {
    ((float4*)xo)[i] = y;
  } else {
    us4 pk; pk[0] = f2bf(y.x); pk[1] = f2bf(y.y); pk[2] = f2bf(y.z); pk[3] = f2bf(y.w);
    *(us4*)(xb + (size_t)i * 4) = pk;
  }
}

// ---------------- setup kernels ----------------------------------------------
__global__ __launch_bounds__(256)
void conv_bf16(const float* __restrict__ s, u16* __restrict__ d, int n4)
{
  const int i = blockIdx.x * 256 + threadIdx.x;
  if (i >= n4) return;
  float4 v = ((const float4*)s)[i];
  us4 pk; pk[0] = f2bf(v.x); pk[1] = f2bf(v.y); pk[2] = f2bf(v.z); pk[3] = f2bf(v.w);
  *(us4*)(d + (size_t)i * 4) = pk;
}

__global__ __launch_bounds__(256)
void conv_qkvw(const float* __restrict__ wq, const float* __restrict__ wk,
               const float* __restrict__ wv, u16* __restrict__ d)
{
  const int i = blockIdx.x * 256 + threadIdx.x;
  const int per = QKVN * DM / 4;
  const int l = i / per;
  const int rem = i - l * per;
  const int r = rem / (DM / 4);
  const int cv = rem - r * (DM / 4);
  const float* srcrow;
  if (r < DM)          srcrow = wq + ((size_t)l * DM + r) * DM;
  else if (r < 2 * DM) srcrow = wk + ((size_t)l * DM + (r - DM)) * DM;
  else                 srcrow = wv + ((size_t)l * DM + (r - 2 * DM)) * DM;
  float4 v = ((const float4*)srcrow)[cv];
  us4 pk; pk[0] = f2bf(v.x); pk[1] = f2bf(v.y); pk[2] = f2bf(v.z); pk[3] = f2bf(v.w);
  *(us4*)(d + (size_t)i * 4) = pk;
}

__global__ __launch_bounds__(256)
void conv_bias_qkv(const float* __restrict__ bq, const float* __restrict__ bk,
                   const float* __restrict__ bv, float* __restrict__ d)
{
  const int i = blockIdx.x * 256 + threadIdx.x;
  const int l = i / QKVN;
  const int r = i - l * QKVN;
  float v;
  if (r < DM)          v = bq[l * DM + r];
  else if (r < 2 * DM) v = bk[l * DM + r - DM];
  else                 v = bv[l * DM + r - 2 * DM];
  d[i] = v;
}

__global__ __launch_bounds__(256)
void bias_tr(const float* __restrict__ src, u16* __restrict__ dst)
{
  const int l = blockIdx.x, b = blockIdx.y;
  __shared__ float row[SEQ * NH];
  const float* s = src + ((size_t)b * SEQ + l) * SEQ * NH;
  for (int i = threadIdx.x; i < SEQ * NH; i += 256) row[i] = s[i];
  __syncthreads();
  for (int i = threadIdx.x; i < SEQ * NH; i += 256) {
    const int h = i >> 7, ss = i & 127;
    dst[((size_t)(b * NH + h) * SEQ + l) * SEQ + ss] = f2bf(row[ss * NH + h]);
  }
}

// ---------------- launch -----------------------------------------------------
extern "C" void kernel_launch(void* const* d_in, const int* in_sizes, int n_in,
                              void* d_out, int out_size, void* d_ws, size_t ws_size,
                              hipStream_t stream)
{
  const float* x    = (const float*)d_in[0];
  const float* abia = (const float*)d_in[1];
  const float* Wq   = (const float*)d_in[2];
  const float* bq   = (const float*)d_in[3];
  const float* Wk   = (const float*)d_in[4];
  const float* bk   = (const float*)d_in[5];
  const float* Wv   = (const float*)d_in[6];
  const float* bv   = (const float*)d_in[7];
  const float* Wo   = (const float*)d_in[8];
  const float* bo   = (const float*)d_in[9];
  const float* W1   = (const float*)d_in[10];
  const float* b1   = (const float*)d_in[11];
  const float* W2   = (const float*)d_in[12];
  const float* b2   = (const float*)d_in[13];
  const float* g1   = (const float*)d_in[14];
  const float* be1  = (const float*)d_in[15];
  const float* g2   = (const float*)d_in[16];
  const float* be2  = (const float*)d_in[17];
  const float* gf   = (const float*)d_in[18];
  const float* bef  = (const float*)d_in[19];
  float* out = (float*)d_out;

  char* ws = (char*)d_ws;
  size_t off = 0;
  auto alloc = [&](size_t n) -> char* {
    char* p = ws + off;
    off = (off + n + 255) & ~(size_t)255;
    return p;
  };
  u16*  wqkv  = (u16*)alloc((size_t)3 * QKVN * DM * 2);
  u16*  wo    = (u16*)alloc((size_t)3 * DM * DM * 2);
  u16*  w1    = (u16*)alloc((size_t)3 * FF * DM * 2);
  u16*  w2    = (u16*)alloc((size_t)3 * DM * FF * 2);
  float* bqkv = (float*)alloc((size_t)3 * QKVN * 4);
  u16*  xb    = (u16*)alloc((size_t)MTOK * DM * 2);
  u16*  ab    = (u16*)alloc((size_t)MTOK * DM * 2);
  u16*  big   = (u16*)alloc((size_t)MTOK * FF * 2);
  u16*  biasT = (u16*)alloc((size_t)HEADTOT * SEQ * SEQ * 2);
  float* p1   = (float*)alloc((size_t)112 * DM * 4);
  float* p2   = (float*)alloc((size_t)112 * DM * 4);
  float* sc   = (float*)alloc(DM * 4);
  float* sh   = (float*)alloc(DM * 4);
  if (off > ws_size) return;

  conv_qkvw<<<5184, 256, 0, stream>>>(Wq, Wk, Wv, wqkv);
  conv_bf16<<<1728, 256, 0, stream>>>(Wo, wo, 3 * DM * DM / 4);
  conv_bf16<<<6912, 256, 0, stream>>>(W1, w1, 3 * FF * DM / 4);
  conv_bf16<<<6912, 256, 0, stream>>>(W2, w2, 3 * DM * FF / 4);
  conv_bias_qkv<<<27, 256, 0, stream>>>(bq, bk, bv, bqkv);
  bias_tr<<<dim3(SEQ, NB), 256, 0, stream>>>(abia, biasT);
  conv_bf16<<<MTOK * DM / 4 / 256, 256, 0, stream>>>(x, xb, MTOK * DM / 4);

  auto gemm = [&](int epi, const u16* Ap, const u16* Wp, const float* bp,
                  u16* ob, float* o32, const u16* rs, int M, int N, int K) {
    const int Nt = N / 256;
    const int tiles = (M / 256) * Nt;
    const int tpb = (tiles + 255) / 256;
    const int grid = tiles / tpb;          // exact for all our shapes
    if (epi == 1)
      gemm_bt<1><<<grid, 512, 0, stream>>>(Ap, Wp, bp, ob, o32, rs, p1, p2, M, N, K, Nt, tpb);
    else if (epi == 2)
      gemm_bt<2><<<grid, 512, 0, stream>>>(Ap, Wp, bp, ob, o32, rs, p1, p2, M, N, K, Nt, tpb);
    else
      gemm_bt<3><<<grid, 512, 0, stream>>>(Ap, Wp, bp, ob, o32, rs, p1, p2, M, N, K, Nt, tpb);
  };

  for (int l = 0; l < NLAYER; l++) {
    gemm(3, xb, wqkv + (size_t)l * QKVN * DM, bqkv + l * QKVN, big, nullptr, nullptr,
         MTOK, QKVN, DM);
    attn_kernel<<<dim3(NH, NB), 256, 0, stream>>>(big, biasT, ab);
    gemm(2, ab, wo + (size_t)l * DM * DM, bo + l * DM, nullptr, out, xb,
         MTOK, DM, DM);
    bn_final<false><<<3, 256, 0, stream>>>(p1, p2, g1 + l * DM, be1 + l * DM,
                                           nullptr, nullptr, sc, sh);
    bn_apply<0><<<MTOK * DM / 4 / 256, 256, 0, stream>>>(out, sc, sh, nullptr, xb);
    gemm(1, xb, w1 + (size_t)l * FF * DM, b1 + l * FF, big, nullptr, nullptr,
         MTOK, FF, DM);
    gemm(2, big, w2 + (size_t)l * DM * FF, b2 + l * DM, nullptr, out, xb,
         MTOK, DM, FF);
    if (l < NLAYER - 1) {
      bn_final<false><<<3, 256, 0, stream>>>(p1, p2, g2 + l * DM, be2 + l * DM,
                                             nullptr, nullptr, sc, sh);
      bn_apply<0><<<MTOK * DM / 4 / 256, 256, 0, stream>>>(out, sc, sh, nullptr, xb);
    } else {
      bn_final<true><<<3, 256, 0, stream>>>(p1, p2, g2 + l * DM, be2 + l * DM,
                                            gf, bef, sc, sh);
      bn_apply<1><<<MTOK * DM / 4 / 256, 256, 0, stream>>>(out, sc, sh, out, nullptr);
    }
  }
}

// Round 11
// 1150.812 us; speedup vs baseline: 2.1315x; 1.0170x over previous
//
#include <hip/hip_runtime.h>

#define NB 112
#define SEQ 128
#define DM 768
#define NH 12
#define HD 64
#define FF 3072
#define NLAYER 3
#define MTOK (NB*SEQ)            // 14336
#define QKVN (3*DM)              // 2304
#define HEADTOT (NB*NH)          // 1344
#define QSZ ((size_t)HEADTOT*SEQ*HD)   // 11010048 elems per q/k/v

typedef unsigned short u16;
typedef __attribute__((ext_vector_type(8))) short short8;
typedef __attribute__((ext_vector_type(4))) float f32x4;
typedef __attribute__((ext_vector_type(4))) unsigned short us4;

__device__ __forceinline__ u16 f2bf(float f){
  unsigned u = __builtin_bit_cast(unsigned, f);
  u += 0x7FFFu + ((u >> 16) & 1u);
  return (u16)(u >> 16);
}
__device__ __forceinline__ float bf2f(u16 b){
  unsigned u = ((unsigned)b) << 16;
  return __builtin_bit_cast(float, u);
}
// packed RNE f32x2 -> bf16x2 (lo=s0, hi=s1)
__device__ __forceinline__ unsigned cvt_pk_bf16(float lo, float hi){
  unsigned r;
  asm("v_cvt_pk_bf16_f32 %0, %1, %2" : "=v"(r) : "v"(lo), "v"(hi));
  return r;
}
// tanh-GELU in sigmoid form: 0.5x(1+tanh(z)) == x / (1 + e^{-2z})
__device__ __forceinline__ float gelu_t(float x){
  const float t = -1.5957691216057308f * x * __builtin_fmaf(0.044715f, x*x, 1.0f);
  return __fdividef(x, 1.0f + __expf(t));
}

__device__ __forceinline__ void gl_lds16(const void* g, void* l){
  __builtin_amdgcn_global_load_lds((const __attribute__((address_space(1))) unsigned*)g,
                                   (__attribute__((address_space(3))) unsigned*)l, 16, 0, 0);
}

// ================= persistent 256x256 GEMM, 2 merged phases/K-tile ==========
// C[m,n] = sum_k A[m,k]*W[n,k]. 512 thr = 8 waves (2M x 4N).
// Same staging/data schedule and vmcnt accounting as the verified 4-phase
// version (r10 = 1170 us), but phases merged pairwise: PA = mh0 x {k0,k1}
// (32 MFMA), PB = mh1 x {k0,k1}. Barriers/iter: 8 -> 4. Stage calls and
// their positions relative to the waits are UNCHANGED:
//   PA stages B0(t+1), B1(t+1);   after MFMA: vmcnt(4) (drains t-1's A loads)
//   PB stages A0(t+2), A1(t+1);   after MFMA: vmcnt(4)/(2) (drains B(t+1))
// EPI: 1 = gelu(acc+bias)->bf16 ; 2 = y=acc+bias+res(bf16) -> f32 + BN partials ;
//      3 = qkv head-scatter bf16
template<int EPI>
__global__ __launch_bounds__(512, 2)
void gemm_bt(const u16* __restrict__ A, const u16* __restrict__ W,
             const float* __restrict__ bias, u16* __restrict__ obf,
             float* __restrict__ of32, const u16* __restrict__ res,
             float* __restrict__ p1, float* __restrict__ p2,
             int M, int N, int K, int Nt, int TPB)
{
  __shared__ __align__(16) char smem[131072];
  const int tid = threadIdx.x;
  const int w = tid >> 6, lane = tid & 63;
  const int wm = w >> 2, wn = w & 3;
  const int fr = lane & 15, fg = lane >> 4;
  const int fko = fg * 8;
  const int grid = gridDim.x;
  const int q8 = grid >> 3, r8 = grid & 7;
  const int xcd = blockIdx.x & 7, pos = blockIdx.x >> 3;
  const int start = xcd < r8 ? xcd * (q8 + 1) : r8 * (q8 + 1) + (xcd - r8) * q8;
  const int swz = start + pos;
  const int nt = K >> 6;
  const int tot = TPB * nt;
  const int l3 = lane >> 3;
  const int k16s = ((lane & 7) ^ l3) * 8;
  int rowAK[2][2], rowBK[2][2];
  #pragma unroll
  for (int mh = 0; mh < 2; mh++)
    #pragma unroll
    for (int j = 0; j < 2; j++)
      rowAK[mh][j] = (mh*64 + j*128 + w*8 + l3) * K;
  #pragma unroll
  for (int h = 0; h < 2; h++)
    #pragma unroll
    for (int j = 0; j < 2; j++)
      rowBK[h][j] = (h*128 + (w + j*8)*8 + l3) * K;

  auto stA2 = [&](int bb, int mh, int soff) {
    const u16* g0 = A + (size_t)soff + rowAK[mh][0] + k16s;
    const u16* g1 = A + (size_t)soff + rowAK[mh][1] + k16s;
    char* d = smem + bb*65536 + (mh*64 + w*8)*128;
    gl_lds16(g0, d);
    gl_lds16(g1, d + 16384);
  };
  auto stB2 = [&](int bb, int h, int soff) {
    const u16* g0 = W + (size_t)soff + rowBK[h][0] + k16s;
    const u16* g1 = W + (size_t)soff + rowBK[h][1] + k16s;
    char* d = smem + bb*65536 + 32768 + (h*128 + w*8)*128;
    gl_lds16(g0, d);
    gl_lds16(g1, d + 8192);
  };
  const int axor = (fr & 7) << 4;
  auto rdA2 = [&](int bb, int mh, int kh, int mf) -> short8 {
    const int row = wm*128 + mh*64 + mf*16 + fr;
    return *(const short8*)(smem + bb*65536 + row*128 + (((kh*32 + fko)*2) ^ axor));
  };
  auto rdB2 = [&](int bb, int kh, int nf) -> short8 {
    const int row = wn*64 + nf*16 + fr;
    return *(const short8*)(smem + bb*65536 + 32768 + row*128 + (((kh*32 + fko)*2) ^ axor));
  };
  auto coord = [&](int r, int& bm, int& bn) {
    const int lin = swz * TPB + r;
    const int mI = lin / Nt;
    bm = mI * 256; bn = (lin - mI * Nt) * 256;
  };

  f32x4 acc[8][4] = {};

  auto epi = [&](int bm, int bn) {
    float bs[4] = {0,0,0,0}, bq[4] = {0,0,0,0};
    #pragma unroll
    for (int mi = 0; mi < 8; mi++) {
      #pragma unroll
      for (int ni = 0; ni < 4; ni++) {
        const int c = bn + wn*64 + ni*16 + fr;
        const int r0 = bm + wm*128 + (mi>>2)*64 + (mi&3)*16 + fg*4;
        const float bc = bias[c];
        float v[4];
        #pragma unroll
        for (int j = 0; j < 4; j++) v[j] = acc[mi][ni][j] + bc;
        if constexpr (EPI == 1) {
          #pragma unroll
          for (int j = 0; j < 4; j++) v[j] = gelu_t(v[j]);
          const unsigned p01 = cvt_pk_bf16(v[0], v[1]);
          const unsigned p23 = cvt_pk_bf16(v[2], v[3]);
          u16* d = obf + (size_t)r0 * N + c;
          d[0] = (u16)p01; d[N] = (u16)(p01 >> 16);
          d[2*N] = (u16)p23; d[3*N] = (u16)(p23 >> 16);
        } else if constexpr (EPI == 2) {
          #pragma unroll
          for (int j = 0; j < 4; j++) {
            const float y = v[j] + bf2f(res[(size_t)(r0+j) * N + c]);
            of32[(size_t)(r0+j) * N + c] = y;
            bs[ni] += y; bq[ni] += y * y;
          }
        } else {
          const int which = c / DM;
          const int cc = c - which * DM;
          const int hh = cc >> 6, e = cc & 63;
          const int bb = r0 >> 7, l = r0 & 127;
          const unsigned p01 = cvt_pk_bf16(v[0], v[1]);
          const unsigned p23 = cvt_pk_bf16(v[2], v[3]);
          u16* d = obf + (size_t)which * QSZ + ((size_t)(bb*NH + hh) * SEQ + l) * HD + e;
          d[0] = (u16)p01; d[HD] = (u16)(p01 >> 16);
          d[2*HD] = (u16)p23; d[3*HD] = (u16)(p23 >> 16);
        }
        acc[mi][ni] = (f32x4){0.f, 0.f, 0.f, 0.f};
      }
    }
    if constexpr (EPI == 2) {
      const int mIdx = bm >> 8;
      #pragma unroll
      for (int ni = 0; ni < 4; ni++) {
        float s = bs[ni], qq = bq[ni];
        s  += __shfl_xor(s, 16);  s  += __shfl_xor(s, 32);
        qq += __shfl_xor(qq, 16); qq += __shfl_xor(qq, 32);
        if (fg == 0) {
          const int c = bn + wn*64 + ni*16 + fr;
          p1[(mIdx*2 + wm) * N + c] = s;
          p2[(mIdx*2 + wm) * N + c] = qq;
        }
      }
    }
  };

  int r0t = 0, kt0 = 0, bm0, bn0; coord(0, bm0, bn0);
  int r1 = 0, kt1 = 1, bm1 = bm0, bn1 = bn0;
  int r2 = 0, kt2 = 2, bm2 = bm0;
  if (kt2 >= nt) { kt2 -= nt; r2 = 1; int d; if (r2 < TPB) coord(r2, bm2, d); }

  stA2(0, 0, bm0*K); stA2(0, 1, bm0*K);
  stB2(0, 0, bn0*K); stB2(0, 1, bn0*K);
  if (tot > 1) stA2(1, 0, bm1*K + kt1*64);
  asm volatile("s_waitcnt vmcnt(2)" ::: "memory");
  __builtin_amdgcn_s_barrier();

  short8 a0[4], a1[4], bk0[4], bk1[4];
  for (int it = 0; it < tot; ++it) {
    const int bufc = it & 1, nb = bufc ^ 1;
    const bool st1 = (it + 1 < tot), st2 = (it + 2 < tot);
    const int sB1 = bn1*K + kt1*64;
    const int sA1 = bm1*K + kt1*64;
    const int sA2 = bm2*K + kt2*64;
    // ---------------- PA: mh0 x {k0,k1}  (32 MFMA) ----------------
    #pragma unroll
    for (int i = 0; i < 4; i++) a0[i] = rdA2(bufc, 0, 0, i);
    #pragma unroll
    for (int i = 0; i < 4; i++) a1[i] = rdA2(bufc, 0, 1, i);
    #pragma unroll
    for (int i = 0; i < 4; i++) bk0[i] = rdB2(bufc, 0, i);
    #pragma unroll
    for (int i = 0; i < 4; i++) bk1[i] = rdB2(bufc, 1, i);
    if (st1) { stB2(nb, 0, sB1); stB2(nb, 1, sB1); }
    __builtin_amdgcn_s_barrier();
    asm volatile("s_waitcnt lgkmcnt(0)" ::: "memory");
    __builtin_amdgcn_sched_barrier(0);
    __builtin_amdgcn_s_setprio(1);
    #pragma unroll
    for (int mi = 0; mi < 4; mi++)
      #pragma unroll
      for (int ni = 0; ni < 4; ni++)
        acc[mi][ni] = __builtin_amdgcn_mfma_f32_16x16x32_bf16(a0[mi], bk0[ni], acc[mi][ni], 0, 0, 0);
    #pragma unroll
    for (int mi = 0; mi < 4; mi++)
      #pragma unroll
      for (int ni = 0; ni < 4; ni++)
        acc[mi][ni] = __builtin_amdgcn_mfma_f32_16x16x32_bf16(a1[mi], bk1[ni], acc[mi][ni], 0, 0, 0);
    __builtin_amdgcn_s_setprio(0);
    if (st1) { asm volatile("s_waitcnt vmcnt(4)" ::: "memory"); }
    else     { asm volatile("s_waitcnt vmcnt(0)" ::: "memory"); }
    __builtin_amdgcn_s_barrier();
    // ---------------- PB: mh1 x {k0,k1}  (32 MFMA) ----------------
    #pragma unroll
    for (int i = 0; i < 4; i++) a0[i] = rdA2(bufc, 1, 0, i);
    #pragma unroll
    for (int i = 0; i < 4; i++) a1[i] = rdA2(bufc, 1, 1, i);
    if (st2) stA2(bufc, 0, sA2);
    if (st1) stA2(nb, 1, sA1);
    __builtin_amdgcn_s_barrier();
    asm volatile("s_waitcnt lgkmcnt(0)" ::: "memory");
    __builtin_amdgcn_sched_barrier(0);
    __builtin_amdgcn_s_setprio(1);
    #pragma unroll
    for (int mi = 0; mi < 4; mi++)
      #pragma unroll
      for (int ni = 0; ni < 4; ni++)
        acc[4+mi][ni] = __builtin_amdgcn_mfma_f32_16x16x32_bf16(a0[mi], bk0[ni], acc[4+mi][ni], 0, 0, 0);
    #pragma unroll
    for (int mi = 0; mi < 4; mi++)
      #pragma unroll
      for (int ni = 0; ni < 4; ni++)
        acc[4+mi][ni] = __builtin_amdgcn_mfma_f32_16x16x32_bf16(a1[mi], bk1[ni], acc[4+mi][ni], 0, 0, 0);
    __builtin_amdgcn_s_setprio(0);
    if (st2)      { asm volatile("s_waitcnt vmcnt(4)" ::: "memory"); }
    else if (st1) { asm volatile("s_waitcnt vmcnt(2)" ::: "memory"); }
    __builtin_amdgcn_s_barrier();
    // tile boundary: whole-tile epilogue AFTER the counted wait + barrier
    if (kt0 == nt - 1) {
      epi(bm0, bn0);
      kt0 = 0; r0t++;
      if (r0t < TPB) coord(r0t, bm0, bn0);
    } else kt0++;
    kt1++; if (kt1 == nt) { kt1 = 0; r1++; if (r1 < TPB) coord(r1, bm1, bn1); }
    kt2++; if (kt2 == nt) { kt2 = 0; r2++; if (r2 < TPB) { int d; coord(r2, bm2, d); } }
  }
}

// ---------------- Attention: one block per (b,h) -----------------------------
__global__ __launch_bounds__(256)
void attn_kernel(const u16* __restrict__ qkvb, const u16* __restrict__ biasT,
                 u16* __restrict__ ab)
{
  const int h = blockIdx.x, b = blockIdx.y;
  const int tid = threadIdx.x, w = tid >> 6, lane = tid & 63;
  const int bh = b * NH + h;
  const u16* qp = qkvb + (size_t)bh * SEQ * HD;
  const u16* kp = qkvb + QSZ + (size_t)bh * SEQ * HD;
  const u16* vp = qkvb + 2 * QSZ + (size_t)bh * SEQ * HD;
  __shared__ __align__(16) u16 vT[HD * 136];
  __shared__ __align__(16) u16 P[SEQ * 136];
  {
    const int s = tid & 127, half = tid >> 7;
    #pragma unroll
    for (int rr = 0; rr < 4; rr++) {
      const int e0 = half * 32 + rr * 8;
      short8 v8 = *(const short8*)&vp[s * HD + e0];
      #pragma unroll
      for (int j = 0; j < 8; j++) vT[(e0 + j) * 136 + s] = (u16)v8[j];
    }
  }
  const int fr = lane & 15, fg = lane >> 4;
  f32x4 sacc[2][8] = {};
  #pragma unroll
  for (int ks = 0; ks < 2; ks++) {
    const int k0 = ks * 32 + fg * 8;
    short8 qf[2], kf[8];
    #pragma unroll
    for (int mi = 0; mi < 2; mi++) qf[mi] = *(const short8*)&qp[(w*32 + mi*16 + fr) * HD + k0];
    #pragma unroll
    for (int ni = 0; ni < 8; ni++) kf[ni] = *(const short8*)&kp[(ni*16 + fr) * HD + k0];
    #pragma unroll
    for (int mi = 0; mi < 2; mi++)
      #pragma unroll
      for (int ni = 0; ni < 8; ni++)
        sacc[mi][ni] = __builtin_amdgcn_mfma_f32_16x16x32_bf16(qf[mi], kf[ni], sacc[mi][ni], 0, 0, 0);
  }
  const u16* bt = biasT + (size_t)bh * SEQ * SEQ;
  #pragma unroll
  for (int mi = 0; mi < 2; mi++) {
    #pragma unroll
    for (int j = 0; j < 4; j++) {
      const int l = w*32 + mi*16 + fg*4 + j;
      float vals[8];
      float mx = -1e30f;
      #pragma unroll
      for (int ni = 0; ni < 8; ni++) {
        vals[ni] = sacc[mi][ni][j] * 0.125f + bf2f(bt[l * SEQ + ni*16 + fr]);
        mx = fmaxf(mx, vals[ni]);
      }
      #pragma unroll
      for (int d = 1; d < 16; d <<= 1) mx = fmaxf(mx, __shfl_xor(mx, d));
      float sum = 0.f;
      #pragma unroll
      for (int ni = 0; ni < 8; ni++) { vals[ni] = __expf(vals[ni] - mx); sum += vals[ni]; }
      #pragma unroll
      for (int d = 1; d < 16; d <<= 1) sum += __shfl_xor(sum, d);
      const float inv = 1.0f / sum;
      #pragma unroll
      for (int ni = 0; ni < 8; ni++) P[l * 136 + ni*16 + fr] = f2bf(vals[ni] * inv);
    }
  }
  __syncthreads();
  f32x4 oacc[2][4] = {};
  #pragma unroll
  for (int ss = 0; ss < 4; ss++) {
    const int s0 = ss * 32 + fg * 8;
    short8 pf[2], vf[4];
    #pragma unroll
    for (int mi = 0; mi < 2; mi++) pf[mi] = *(const short8*)&P[(w*32 + mi*16 + fr) * 136 + s0];
    #pragma unroll
    for (int ei = 0; ei < 4; ei++) vf[ei] = *(const short8*)&vT[(ei*16 + fr) * 136 + s0];
    #pragma unroll
    for (int mi = 0; mi < 2; mi++)
      #pragma unroll
      for (int ei = 0; ei < 4; ei++)
        oacc[mi][ei] = __builtin_amdgcn_mfma_f32_16x16x32_bf16(pf[mi], vf[ei], oacc[mi][ei], 0, 0, 0);
  }
  #pragma unroll
  for (int mi = 0; mi < 2; mi++)
    #pragma unroll
    for (int ei = 0; ei < 4; ei++)
      #pragma unroll
      for (int j = 0; j < 4; j++) {
        const int r = b * SEQ + w*32 + mi*16 + fg*4 + j;
        const int c = h * HD + ei*16 + fr;
        ab[(size_t)r * DM + c] = f2bf(oacc[mi][ei][j]);
      }
}

// ---------------- BatchNorm finalize from fused partials ---------------------
template<bool FINAL>
__global__ __launch_bounds__(256)
void bn_final(const float* __restrict__ p1, const float* __restrict__ p2,
              const float* __restrict__ ga, const float* __restrict__ be,
              const float* __restrict__ gb, const float* __restrict__ beb,
              float* __restrict__ sc, float* __restrict__ sh)
{
  const int c = blockIdx.x * 256 + threadIdx.x;
  float s = 0, q = 0;
  for (int i = 0; i < 112; i++) { s += p1[i * DM + c]; q += p2[i * DM + c]; }
  const float mean = s * (1.0f / MTOK);
  const float var = q * (1.0f / MTOK) - mean * mean;
  const float rstd = rsqrtf(var + 1e-5f);
  if constexpr (!FINAL) {
    const float g = ga[c] * rstd;
    sc[c] = g;
    sh[c] = be[c] - mean * g;
  } else {
    const float sc2 = ga[c] * rstd;
    const float sh2 = be[c] - mean * sc2;
    const float varf = sc2 * sc2 * var;
    const float meanf = sc2 * mean + sh2;
    const float scf = gb[c] * rsqrtf(varf + 1e-5f);
    const float shf = beb[c] - meanf * scf;
    sc[c] = scf * sc2;
    sh[c] = scf * sh2 + shf;
  }
}

// MODE 0: write xb (bf16) only (intermediate); MODE 1: write out f32 (final)
template<int MODE>
__global__ __launch_bounds__(256)
void bn_apply(const float* __restrict__ xi, const float* __restrict__ sc,
              const float* __restrict__ sh, float* __restrict__ xo, u16* __restrict__ xb)
{
  const int i = blockIdx.x * 256 + threadIdx.x;
  const int cv = i % (DM / 4);
  float4 v = ((const float4*)xi)[i];
  const float4 s = ((const float4*)sc)[cv];
  const float4 h = ((const float4*)sh)[cv];
  float4 y;
  y.x = v.x * s.x + h.x; y.y = v.y * s.y + h.y;
  y.z = v.z * s.z + h.z; y.w = v.w * s.w + h.w;
  if constexpr (MODE == 1) {
    ((float4*)xo)[i] = y;
  } else {
    us4 pk; pk[0] = f2bf(y.x); pk[1] = f2bf(y.y); pk[2] = f2bf(y.z); pk[3] = f2bf(y.w);
    *(us4*)(xb + (size_t)i * 4) = pk;
  }
}

// ---------------- setup kernels ----------------------------------------------
__global__ __launch_bounds__(256)
void conv_bf16(const float* __restrict__ s, u16* __restrict__ d, int n4)
{
  const int i = blockIdx.x * 256 + threadIdx.x;
  if (i >= n4) return;
  float4 v = ((const float4*)s)[i];
  us4 pk; pk[0] = f2bf(v.x); pk[1] = f2bf(v.y); pk[2] = f2bf(v.z); pk[3] = f2bf(v.w);
  *(us4*)(d + (size_t)i * 4) = pk;
}

__global__ __launch_bounds__(256)
void conv_qkvw(const float* __restrict__ wq, const float* __restrict__ wk,
               const float* __restrict__ wv, u16* __restrict__ d)
{
  const int i = blockIdx.x * 256 + threadIdx.x;
  const int per = QKVN * DM / 4;
  const int l = i / per;
  const int rem = i - l * per;
  const int r = rem / (DM / 4);
  const int cv = rem - r * (DM / 4);
  const float* srcrow;
  if (r < DM)          srcrow = wq + ((size_t)l * DM + r) * DM;
  else if (r < 2 * DM) srcrow = wk + ((size_t)l * DM + (r - DM)) * DM;
  else                 srcrow = wv + ((size_t)l * DM + (r - 2 * DM)) * DM;
  float4 v = ((const float4*)srcrow)[cv];
  us4 pk; pk[0] = f2bf(v.x); pk[1] = f2bf(v.y); pk[2] = f2bf(v.z); pk[3] = f2bf(v.w);
  *(us4*)(d + (size_t)i * 4) = pk;
}

__global__ __launch_bounds__(256)
void conv_bias_qkv(const float* __restrict__ bq, const float* __restrict__ bk,
                   const float* __restrict__ bv, float* __restrict__ d)
{
  const int i = blockIdx.x * 256 + threadIdx.x;
  const int l = i / QKVN;
  const int r = i - l * QKVN;
  float v;
  if (r < DM)          v = bq[l * DM + r];
  else if (r < 2 * DM) v = bk[l * DM + r - DM];
  else                 v = bv[l * DM + r - 2 * DM];
  d[i] = v;
}

__global__ __launch_bounds__(256)
void bias_tr(const float* __restrict__ src, u16* __restrict__ dst)
{
  const int l = blockIdx.x, b = blockIdx.y;
  __shared__ float row[SEQ * NH];
  const float* s = src + ((size_t)b * SEQ + l) * SEQ * NH;
  for (int i = threadIdx.x; i < SEQ * NH; i += 256) row[i] = s[i];
  __syncthreads();
  for (int i = threadIdx.x; i < SEQ * NH; i += 256) {
    const int h = i >> 7, ss = i & 127;
    dst[((size_t)(b * NH + h) * SEQ + l) * SEQ + ss] = f2bf(row[ss * NH + h]);
  }
}

// ---------------- launch -----------------------------------------------------
extern "C" void kernel_launch(void* const* d_in, const int* in_sizes, int n_in,
                              void* d_out, int out_size, void* d_ws, size_t ws_size,
                              hipStream_t stream)
{
  const float* x    = (const float*)d_in[0];
  const float* abia = (const float*)d_in[1];
  const float* Wq   = (const float*)d_in[2];
  const float* bq   = (const float*)d_in[3];
  const float* Wk   = (const float*)d_in[4];
  const float* bk   = (const float*)d_in[5];
  const float* Wv   = (const float*)d_in[6];
  const float* bv   = (const float*)d_in[7];
  const float* Wo   = (const float*)d_in[8];
  const float* bo   = (const float*)d_in[9];
  const float* W1   = (const float*)d_in[10];
  const float* b1   = (const float*)d_in[11];
  const float* W2   = (const float*)d_in[12];
  const float* b2   = (const float*)d_in[13];
  const float* g1   = (const float*)d_in[14];
  const float* be1  = (const float*)d_in[15];
  const float* g2   = (const float*)d_in[16];
  const float* be2  = (const float*)d_in[17];
  const float* gf   = (const float*)d_in[18];
  const float* bef  = (const float*)d_in[19];
  float* out = (float*)d_out;

  char* ws = (char*)d_ws;
  size_t off = 0;
  auto alloc = [&](size_t n) -> char* {
    char* p = ws + off;
    off = (off + n + 255) & ~(size_t)255;
    return p;
  };
  u16*  wqkv  = (u16*)alloc((size_t)3 * QKVN * DM * 2);
  u16*  wo    = (u16*)alloc((size_t)3 * DM * DM * 2);
  u16*  w1    = (u16*)alloc((size_t)3 * FF * DM * 2);
  u16*  w2    = (u16*)alloc((size_t)3 * DM * FF * 2);
  float* bqkv = (float*)alloc((size_t)3 * QKVN * 4);
  u16*  xb    = (u16*)alloc((size_t)MTOK * DM * 2);
  u16*  ab    = (u16*)alloc((size_t)MTOK * DM * 2);
  u16*  big   = (u16*)alloc((size_t)MTOK * FF * 2);
  u16*  biasT = (u16*)alloc((size_t)HEADTOT * SEQ * SEQ * 2);
  float* p1   = (float*)alloc((size_t)112 * DM * 4);
  float* p2   = (float*)alloc((size_t)112 * DM * 4);
  float* sc   = (float*)alloc(DM * 4);
  float* sh   = (float*)alloc(DM * 4);
  if (off > ws_size) return;

  conv_qkvw<<<5184, 256, 0, stream>>>(Wq, Wk, Wv, wqkv);
  conv_bf16<<<1728, 256, 0, stream>>>(Wo, wo, 3 * DM * DM / 4);
  conv_bf16<<<6912, 256, 0, stream>>>(W1, w1, 3 * FF * DM / 4);
  conv_bf16<<<6912, 256, 0, stream>>>(W2, w2, 3 * DM * FF / 4);
  conv_bias_qkv<<<27, 256, 0, stream>>>(bq, bk, bv, bqkv);
  bias_tr<<<dim3(SEQ, NB), 256, 0, stream>>>(abia, biasT);
  conv_bf16<<<MTOK * DM / 4 / 256, 256, 0, stream>>>(x, xb, MTOK * DM / 4);

  auto gemm = [&](int epi, const u16* Ap, const u16* Wp, const float* bp,
                  u16* ob, float* o32, const u16* rs, int M, int N, int K) {
    const int Nt = N / 256;
    const int tiles = (M / 256) * Nt;
    const int tpb = (tiles + 255) / 256;
    const int grid = tiles / tpb;          // exact for all our shapes
    if (epi == 1)
      gemm_bt<1><<<grid, 512, 0, stream>>>(Ap, Wp, bp, ob, o32, rs, p1, p2, M, N, K, Nt, tpb);
    else if (epi == 2)
      gemm_bt<2><<<grid, 512, 0, stream>>>(Ap, Wp, bp, ob, o32, rs, p1, p2, M, N, K, Nt, tpb);
    else
      gemm_bt<3><<<grid, 512, 0, stream>>>(Ap, Wp, bp, ob, o32, rs, p1, p2, M, N, K, Nt, tpb);
  };

  for (int l = 0; l < NLAYER; l++) {
    gemm(3, xb, wqkv + (size_t)l * QKVN * DM, bqkv + l * QKVN, big, nullptr, nullptr,
         MTOK, QKVN, DM);
    attn_kernel<<<dim3(NH, NB), 256, 0, stream>>>(big, biasT, ab);
    gemm(2, ab, wo + (size_t)l * DM * DM, bo + l * DM, nullptr, out, xb,
         MTOK, DM, DM);
    bn_final<false><<<3, 256, 0, stream>>>(p1, p2, g1 + l * DM, be1 + l * DM,
                                           nullptr, nullptr, sc, sh);
    bn_apply<0><<<MTOK * DM / 4 / 256, 256, 0, stream>>>(out, sc, sh, nullptr, xb);
    gemm(1, xb, w1 + (size_t)l * FF * DM, b1 + l * FF, big, nullptr, nullptr,
         MTOK, FF, DM);
    gemm(2, big, w2 + (size_t)l * DM * FF, b2 + l * DM, nullptr, out, xb,
         MTOK, DM, FF);
    if (l < NLAYER - 1) {
      bn_final<false><<<3, 256, 0, stream>>>(p1, p2, g2 + l * DM, be2 + l * DM,
                                             nullptr, nullptr, sc, sh);
      bn_apply<0><<<MTOK * DM / 4 / 256, 256, 0, stream>>>(out, sc, sh, nullptr, xb);
    } else {
      bn_final<true><<<3, 256, 0, stream>>>(p1, p2, g2 + l * DM, be2 + l * DM,
                                            gf, bef, sc, sh);
      bn_apply<1><<<MTOK * DM / 4 / 256, 256, 0, stream>>>(out, sc, sh, out, nullptr);
    }
  }
}